// Round 11
// baseline (788.832 us; speedup 1.0000x reference)
//
#include <hip/hip_runtime.h>
#include <hip/hip_bf16.h>
#include <cstdint>

typedef _Float16 half8 __attribute__((ext_vector_type(8)));
typedef _Float16 half4 __attribute__((ext_vector_type(4)));
typedef float f32x4 __attribute__((ext_vector_type(4)));

__device__ __forceinline__ void gload_lds16(const _Float16* g, _Float16* l) {
  __builtin_amdgcn_global_load_lds(
      (const __attribute__((address_space(1))) void*)g,
      (__attribute__((address_space(3))) void*)l, 16, 0, 0);
}

// LDS col swizzle for 32-elem (64 B) rows, 16 B granular, involution.
#define KSWZ(r) ((((r) >> 1) & 3) << 3)

// ---------------- weight transpose: WT[n][k] = W[k][n], f32 -> f16 ----------------
__global__ __launch_bounds__(256) void wtrans(const float* __restrict__ W,
                                              _Float16* __restrict__ WT, int K, int N) {
  int idx = blockIdx.x * 256 + threadIdx.x;
  if (idx >= K * N) return;
  int k = idx / N, n = idx - k * N;
  WT[(size_t)n * K + k] = (_Float16)W[idx];
}

// ---------------- blur bilinear upsample 32x32 -> 128x128, windowed [nw][64] ------
__global__ __launch_bounds__(256) void blur_prep(const float* __restrict__ bm,
                                                 float* __restrict__ bw) {
  int idx = blockIdx.x * 256 + threadIdx.x;   // 0..131071
  int wi = idx >> 6, t = idx & 63;
  int b = wi >> 8, wid = wi & 255;
  int hw = wid >> 4, ww = wid & 15;
  int hh = hw * 8 + (t >> 3), www = ww * 8 + (t & 7);
  float yf = (hh + 0.5f) * 0.25f - 0.5f;
  float xf = (www + 0.5f) * 0.25f - 0.5f;
  float yfl = floorf(yf), xfl = floorf(xf);
  float fy = yf - yfl, fx = xf - xfl;
  int y0 = (int)yfl, x0 = (int)xfl;
  int y1 = y0 + 1, x1 = x0 + 1;
  if (y0 < 0) y0 = 0; if (x0 < 0) x0 = 0;
  if (y1 > 31) y1 = 31; if (x1 > 31) x1 = 31;
  const float* p = bm + (size_t)b * 1024;
  float v00 = p[y0 * 32 + x0], v01 = p[y0 * 32 + x1];
  float v10 = p[y1 * 32 + x0], v11 = p[y1 * 32 + x1];
  float v0 = v00 + fx * (v01 - v00);
  float v1 = v10 + fx * (v11 - v10);
  bw[idx] = v0 + fy * (v1 - v0);
}

// ---------------- gather x [B,C,H,W] f32 -> xw [nw*64][256] f16 -------------------
__global__ __launch_bounds__(256) void gather_x(const float* __restrict__ x,
                                                _Float16* __restrict__ xw) {
  const int c0 = blockIdx.x << 6;   // 0,64,128,192
  const int hh = blockIdx.y;        // 0..127
  const int b  = blockIdx.z;        // 0..7
  __shared__ float tile[64][133];
  const int tid = threadIdx.x;
  {
    const int cl = tid >> 7, p = tid & 127;
    const float* xp = x + ((size_t)(b * 256 + c0) * 128 + hh) * 128 + p;
#pragma unroll
    for (int i = 0; i < 32; ++i) {
      int c = i * 2 + cl;
      tile[c][p] = xp[(size_t)c * 16384];
    }
  }
  __syncthreads();
  const int w = tid >> 6, lane = tid & 63;
  const int hw = hh >> 3, ts = hh & 7;
#pragma unroll
  for (int i = 0; i < 32; ++i) {
    int pp = i * 4 + w;
    int row = ((b * 256 + hw * 16 + (pp >> 3)) << 6) + ts * 8 + (pp & 7);
    xw[(size_t)row * 256 + c0 + lane] = (_Float16)tile[lane][pp];
  }
}

// ---------------- scatter x2 [nw*64][256] f16 -> out [B,C,H,W] f32 ----------------
__global__ __launch_bounds__(256) void scatter_out(const _Float16* __restrict__ x2,
                                                   float* __restrict__ out) {
  const int c0 = blockIdx.x << 6;
  const int hh = blockIdx.y;
  const int b  = blockIdx.z;
  __shared__ float tile[64][133];
  const int tid = threadIdx.x;
  const int w = tid >> 6, lane = tid & 63;
  const int hw = hh >> 3, ts = hh & 7;
#pragma unroll
  for (int i = 0; i < 32; ++i) {
    int pp = i * 4 + w;
    int row = ((b * 256 + hw * 16 + (pp >> 3)) << 6) + ts * 8 + (pp & 7);
    tile[lane][pp] = (float)x2[(size_t)row * 256 + c0 + lane];
  }
  __syncthreads();
  const int cl = tid >> 7, p = tid & 127;
  float* op = out + ((size_t)(b * 256 + c0) * 128 + hh) * 128 + p;
#pragma unroll
  for (int i = 0; i < 32; ++i) {
    int c = i * 2 + cl;
    op[(size_t)c * 16384] = tile[c][p];
  }
}

// ---------------- f16 MFMA GEMM: C[M][N] = A[M][K] * BT[N][K]^T + bias ------------
// 128x128 tile, BK=32, 256 threads. T1 XCD-swizzle; A staged via gload_lds (KSWZ,
// 2-buffer); B-fragments read DIRECTLY from global (weights are L2-resident).
// LDS = 16 KB -> up to 6 blocks/CU resident (occupancy lever).
template<int RELU>
__global__ __launch_bounds__(256) void gemm_f16(const _Float16* __restrict__ A,
    const _Float16* __restrict__ BT, const float* __restrict__ bias,
    _Float16* __restrict__ C, int M, int N, int K) {
  __shared__ _Float16 As[2][128 * 32];
  const int tid = threadIdx.x;
  const int gx = gridDim.x;
  int flat = blockIdx.y * gx + blockIdx.x;
  int nwg = gx * gridDim.y;
  int nb = (nwg & 7) ? flat : ((flat & 7) * (nwg >> 3) + (flat >> 3));
  const int m0 = (nb / gx) << 7;
  const int n0 = (nb % gx) << 7;
  const int w = tid >> 6, lane = tid & 63;
  const int wr = (w >> 1) << 6, wc = (w & 1) << 6;
  const int lr = lane & 15, lg = lane >> 4;
  f32x4 acc[4][4] = {};
  const int sr = tid >> 2, skk = ((tid & 3) << 3) ^ KSWZ(tid >> 2);
  const _Float16* Ag = A + (size_t)(m0 + sr) * K + skk;
  const _Float16* Bg0 = BT + (size_t)(n0 + wc + lr) * K + lg * 8;  // B direct (L2)
  const size_t halfstep = (size_t)64 * K;
  const size_t bstep = (size_t)16 * K;
#define ASTAGE(bufi, k0) do { \
    gload_lds16(Ag + (k0),            &As[bufi][(size_t)tid * 8]); \
    gload_lds16(Ag + (k0) + halfstep, &As[bufi][(size_t)(256 + tid) * 8]); \
  } while (0)
  ASTAGE(0, 0);
  __syncthreads();
  int cur = 0;
  for (int k0 = 0; k0 < K; k0 += 32) {
    if (k0 + 32 < K) ASTAGE(cur ^ 1, k0 + 32);   // async A prefetch
    half8 bf[4];
#pragma unroll
    for (int t = 0; t < 4; ++t)
      bf[t] = *(const half8*)(Bg0 + (size_t)t * bstep + k0);
    half8 af[4];
#pragma unroll
    for (int t = 0; t < 4; ++t) {
      int rowA = wr + t * 16 + lr;
      af[t] = *(const half8*)&As[cur][rowA * 32 + ((lg * 8) ^ KSWZ(rowA))];
    }
#pragma unroll
    for (int i = 0; i < 4; ++i)
#pragma unroll
      for (int j = 0; j < 4; ++j)
        acc[i][j] = __builtin_amdgcn_mfma_f32_16x16x32_f16(af[i], bf[j], acc[i][j], 0, 0, 0);
    __syncthreads();
    cur ^= 1;
  }
#undef ASTAGE
  float bv[4];
#pragma unroll
  for (int j = 0; j < 4; ++j) bv[j] = bias[n0 + wc + j * 16 + lr];
#pragma unroll
  for (int i = 0; i < 4; ++i) {
#pragma unroll
    for (int j = 0; j < 4; ++j) {
      int row = m0 + wr + i * 16 + lg * 4;
      int col = n0 + wc + j * 16 + lr;
      _Float16* cp = C + (size_t)row * N + col;
#pragma unroll
      for (int rr = 0; rr < 4; ++rr) {
        float v = acc[i][j][rr] + bv[j];
        if (RELU) v = fmaxf(v, 0.0f);
        cp[(size_t)rr * N] = (_Float16)v;
      }
    }
  }
}

// ---------------- MFMA attention: one block per window, 4 waves x 2 heads ---------
#define ATT_SWZ(row, col) (((row) << 6) + ((col) ^ (((row) & 7) << 3)))
__global__ __launch_bounds__(256, 3) void attn_mfma(const _Float16* __restrict__ qkv,
    const float* __restrict__ bw, _Float16* __restrict__ o) {
  const int wdw = blockIdx.x;          // window 0..2047
  const int w = threadIdx.x >> 6;      // wave 0..3
  const int lane = threadIdx.x & 63;
  const int lr = lane & 15, lg = lane >> 4;
  __shared__ _Float16 lds_p[4][64 * 64];   // P [64 q][64 k] f16, swizzled
  __shared__ _Float16 lds_v[4][32 * 64];   // V^T [32 d][64 j] f16, swizzled
  _Float16* Pb = lds_p[w];
  _Float16* Vt = lds_v[w];
  const size_t base = (size_t)wdw * 49152;   // 64*768 f16 elems
  f32x4 blv[4];
#pragma unroll
  for (int jt = 0; jt < 4; ++jt) {
    f32x4 bv = *(const f32x4*)&bw[wdw * 64 + jt * 16 + lg * 4];
    blv[jt] = bv * 0.0625f + 0.0625f;
  }
  const f32x4 zero4 = {0.f, 0.f, 0.f, 0.f};
#pragma unroll
  for (int hi = 0; hi < 2; ++hi) {
    const int h = w + hi * 4;
    const size_t qo = base + (size_t)h * 32;
    const _Float16* kp = qkv + qo + 256 + (size_t)lr * 768 + lg * 8;
    const _Float16* qp = qkv + qo +       (size_t)lr * 768 + lg * 8;
    half8 ak[4], bq[4];
#pragma unroll
    for (int t = 0; t < 4; ++t) {
      ak[t] = *(const half8*)(kp + (size_t)t * 16 * 768);
      bq[t] = *(const half8*)(qp + (size_t)t * 16 * 768);
    }
    const _Float16* vp = qkv + qo + 512 + (size_t)lane * 768;
#pragma unroll
    for (int e = 0; e < 4; ++e) {
      half8 vv = *(const half8*)(vp + e * 8);
#pragma unroll
      for (int d = 0; d < 8; ++d) Vt[ATT_SWZ(e * 8 + d, lane)] = vv[d];
    }
    f32x4 cst[4][4];
#pragma unroll
    for (int jt = 0; jt < 4; ++jt)
#pragma unroll
      for (int it = 0; it < 4; ++it)
        cst[jt][it] = __builtin_amdgcn_mfma_f32_16x16x32_f16(ak[jt], bq[it], zero4, 0, 0, 0);
#pragma unroll
    for (int it = 0; it < 4; ++it) {
      float m = -1e30f;
#pragma unroll
      for (int jt = 0; jt < 4; ++jt) {
        cst[jt][it] *= blv[jt];
        m = fmaxf(m, fmaxf(fmaxf(cst[jt][it][0], cst[jt][it][1]),
                           fmaxf(cst[jt][it][2], cst[jt][it][3])));
      }
      m = fmaxf(m, __shfl_xor(m, 16, 64));
      m = fmaxf(m, __shfl_xor(m, 32, 64));
      float s = 0.f;
#pragma unroll
      for (int jt = 0; jt < 4; ++jt)
#pragma unroll
        for (int r = 0; r < 4; ++r) {
          float e = __expf(cst[jt][it][r] - m);
          cst[jt][it][r] = e;
          s += e;
        }
      s += __shfl_xor(s, 16, 64);
      s += __shfl_xor(s, 32, 64);
      float inv = 1.0f / s;
#pragma unroll
      for (int jt = 0; jt < 4; ++jt) {
        half4 pv;
#pragma unroll
        for (int r = 0; r < 4; ++r) pv[r] = (_Float16)(cst[jt][it][r] * inv);
        *(half4*)&Pb[ATT_SWZ(it * 16 + lr, jt * 16 + lg * 4)] = pv;
      }
    }
    f32x4 co[4][2] = {};
#pragma unroll
    for (int ks = 0; ks < 2; ++ks) {
      half8 bv2[2], pa[4];
#pragma unroll
      for (int dt = 0; dt < 2; ++dt)
        bv2[dt] = *(const half8*)&Vt[ATT_SWZ(dt * 16 + lr, ks * 32 + lg * 8)];
#pragma unroll
      for (int it = 0; it < 4; ++it)
        pa[it] = *(const half8*)&Pb[ATT_SWZ(it * 16 + lr, ks * 32 + lg * 8)];
#pragma unroll
      for (int it = 0; it < 4; ++it)
#pragma unroll
        for (int dt = 0; dt < 2; ++dt)
          co[it][dt] = __builtin_amdgcn_mfma_f32_16x16x32_f16(pa[it], bv2[dt], co[it][dt], 0, 0, 0);
    }
#pragma unroll
    for (int it = 0; it < 4; ++it)
#pragma unroll
      for (int dt = 0; dt < 2; ++dt)
#pragma unroll
        for (int r = 0; r < 4; ++r) {
          int row = it * 16 + lg * 4 + r;
          o[((size_t)wdw * 64 + row) * 256 + h * 32 + dt * 16 + lr] =
              (_Float16)co[it][dt][r];
        }
  }
}

// ---------------- out = resid + LayerNorm(inp)*g + b  (wave per row, C=256) -------
__global__ __launch_bounds__(256) void ln_add(const _Float16* __restrict__ inp,
    const _Float16* __restrict__ res, const float* __restrict__ gg,
    const float* __restrict__ bb, _Float16* __restrict__ out) {
  const int w = threadIdx.x >> 6, lane = threadIdx.x & 63;
  const size_t row = (size_t)blockIdx.x * 4 + w;
  half4 v = ((const half4*)(inp + row * 256))[lane];
  float f0 = (float)v[0], f1 = (float)v[1], f2 = (float)v[2], f3 = (float)v[3];
  float s = f0 + f1 + f2 + f3;
  float s2 = f0*f0 + f1*f1 + f2*f2 + f3*f3;
#pragma unroll
  for (int m = 1; m < 64; m <<= 1) {
    s  += __shfl_xor(s, m, 64);
    s2 += __shfl_xor(s2, m, 64);
  }
  float mu = s * 0.00390625f;
  float var = s2 * 0.00390625f - mu * mu;
  float rs = rsqrtf(var + 1e-5f);
  f32x4 gv = *(const f32x4*)(gg + lane * 4);
  f32x4 bv = *(const f32x4*)(bb + lane * 4);
  half4 rv = ((const half4*)(res + row * 256))[lane];
  half4 ov;
  ov[0] = (_Float16)((f0 - mu) * rs * gv[0] + bv[0] + (float)rv[0]);
  ov[1] = (_Float16)((f1 - mu) * rs * gv[1] + bv[1] + (float)rv[1]);
  ov[2] = (_Float16)((f2 - mu) * rs * gv[2] + bv[2] + (float)rv[2]);
  ov[3] = (_Float16)((f3 - mu) * rs * gv[3] + bv[3] + (float)rv[3]);
  ((half4*)(out + row * 256))[lane] = ov;
}

__global__ __launch_bounds__(256) void sentinel(float* out, int n) {
  int i = blockIdx.x * 256 + threadIdx.x;
  if (i < n) out[i] = 12345.0f;
}

extern "C" void kernel_launch(void* const* d_in, const int* in_sizes, int n_in,
                              void* d_out, int out_size, void* d_ws, size_t ws_size,
                              hipStream_t stream) {
  const float* x      = (const float*)d_in[0];
  const float* blurm  = (const float*)d_in[1];
  const float* qkv_w  = (const float*)d_in[2];
  const float* qkv_b  = (const float*)d_in[3];
  const float* proj_w = (const float*)d_in[4];
  const float* proj_b = (const float*)d_in[5];
  const float* ff1_w  = (const float*)d_in[6];
  const float* ff1_b  = (const float*)d_in[7];
  const float* ff2_w  = (const float*)d_in[8];
  const float* ff2_b  = (const float*)d_in[9];
  const float* n1_g   = (const float*)d_in[10];
  const float* n1_b   = (const float*)d_in[11];
  const float* n2_g   = (const float*)d_in[12];
  const float* n2_b   = (const float*)d_in[13];
  float* out = (float*)d_out;

  char* ws = (char*)d_ws;
  constexpr size_t OFF_RA  = 0;                          // qkv f16; later ff1-out f16 (268MB, spans RA+XW+AO)
  constexpr size_t OFF_XW  = 201326592ull;               // xw f16, later x2 f16
  constexpr size_t OFF_AO  = OFF_XW + 67108864ull;       // attn out f16
  constexpr size_t OFF_RC  = OFF_AO + 67108864ull;       // proj out / ff2 out f16
  constexpr size_t OFF_X1  = OFF_RC + 67108864ull;       // x1 f16
  constexpr size_t OFF_QW  = OFF_X1 + 67108864ull;
  constexpr size_t OFF_PW  = OFF_QW + 393216ull;
  constexpr size_t OFF_F1W = OFF_PW + 131072ull;
  constexpr size_t OFF_F2W = OFF_F1W + 524288ull;
  constexpr size_t OFF_BL  = OFF_F2W + 524288ull;
  constexpr size_t NEED    = OFF_BL + 524288ull;
  if (ws_size < NEED) {
    sentinel<<<(out_size + 255) / 256, 256, 0, stream>>>(out, out_size);
    return;
  }
  _Float16* RA   = (_Float16*)(ws + OFF_RA);
  _Float16* F    = (_Float16*)(ws + OFF_RA);   // ff1 out [131072x1024] f16 = 268MB (RA/XW/AO dead)
  _Float16* xw_h = (_Float16*)(ws + OFF_XW);
  _Float16* ao   = (_Float16*)(ws + OFF_AO);
  _Float16* rc   = (_Float16*)(ws + OFF_RC);
  _Float16* x1h  = (_Float16*)(ws + OFF_X1);
  _Float16* qwT  = (_Float16*)(ws + OFF_QW);
  _Float16* pwT  = (_Float16*)(ws + OFF_PW);
  _Float16* f1wT = (_Float16*)(ws + OFF_F1W);
  _Float16* f2wT = (_Float16*)(ws + OFF_F2W);
  float* blurw   = (float*)(ws + OFF_BL);

  wtrans<<<768, 256, 0, stream>>>(qkv_w, qwT, 256, 768);
  wtrans<<<256, 256, 0, stream>>>(proj_w, pwT, 256, 256);
  wtrans<<<1024, 256, 0, stream>>>(ff1_w, f1wT, 256, 1024);
  wtrans<<<1024, 256, 0, stream>>>(ff2_w, f2wT, 1024, 256);
  blur_prep<<<512, 256, 0, stream>>>(blurm, blurw);
  gather_x<<<dim3(4, 128, 8), 256, 0, stream>>>(x, xw_h);

  // qkv = xw @ qkv_w + b          [131072, 768]
  gemm_f16<0><<<dim3(6, 1024), 256, 0, stream>>>(xw_h, qwT, qkv_b, RA, 131072, 768, 256);
  // windowed blur-modulated MFMA attention -> [131072, 256]
  attn_mfma<<<2048, 256, 0, stream>>>(RA, blurw, ao);
  // proj
  gemm_f16<0><<<dim3(2, 1024), 256, 0, stream>>>(ao, pwT, proj_b, rc, 131072, 256, 256);
  // x1 = xw + LN1(proj)
  ln_add<<<32768, 256, 0, stream>>>(rc, xw_h, n1_g, n1_b, x1h);
  // ff single-pass: F = relu(x1 @ ff1_w + b1); rc = F @ ff2_w + b2
  gemm_f16<1><<<dim3(8, 1024), 256, 0, stream>>>(x1h, f1wT, ff1_b, F, 131072, 1024, 256);
  gemm_f16<0><<<dim3(2, 1024), 256, 0, stream>>>(F, f2wT, ff2_b, rc, 131072, 256, 1024);
  // x2 = x1 + LN2(ff2)  (write into xw region; F dead now)
  ln_add<<<32768, 256, 0, stream>>>(rc, x1h, n2_g, n2_b, xw_h);
  scatter_out<<<dim3(4, 128, 8), 256, 0, stream>>>(xw_h, out);
}

// Round 12
// 624.913 us; speedup vs baseline: 1.2623x; 1.2623x over previous
//
#include <hip/hip_runtime.h>
#include <hip/hip_bf16.h>
#include <cstdint>

typedef _Float16 half8 __attribute__((ext_vector_type(8)));
typedef _Float16 half4 __attribute__((ext_vector_type(4)));
typedef float f32x4 __attribute__((ext_vector_type(4)));

__device__ __forceinline__ void gload_lds16(const _Float16* g, _Float16* l) {
  __builtin_amdgcn_global_load_lds(
      (const __attribute__((address_space(1))) void*)g,
      (__attribute__((address_space(3))) void*)l, 16, 0, 0);
}

// LDS col swizzle for 32-elem (64 B) rows, 16 B granular, involution.
#define KSWZ(r) ((((r) >> 1) & 3) << 3)

// ---------------- weight transpose: WT[n][k] = W[k][n], f32 -> f16 ----------------
__global__ __launch_bounds__(256) void wtrans(const float* __restrict__ W,
                                              _Float16* __restrict__ WT, int K, int N) {
  int idx = blockIdx.x * 256 + threadIdx.x;
  if (idx >= K * N) return;
  int k = idx / N, n = idx - k * N;
  WT[(size_t)n * K + k] = (_Float16)W[idx];
}

// ---------------- blur bilinear upsample 32x32 -> 128x128, windowed [nw][64] ------
__global__ __launch_bounds__(256) void blur_prep(const float* __restrict__ bm,
                                                 float* __restrict__ bw) {
  int idx = blockIdx.x * 256 + threadIdx.x;   // 0..131071
  int wi = idx >> 6, t = idx & 63;
  int b = wi >> 8, wid = wi & 255;
  int hw = wid >> 4, ww = wid & 15;
  int hh = hw * 8 + (t >> 3), www = ww * 8 + (t & 7);
  float yf = (hh + 0.5f) * 0.25f - 0.5f;
  float xf = (www + 0.5f) * 0.25f - 0.5f;
  float yfl = floorf(yf), xfl = floorf(xf);
  float fy = yf - yfl, fx = xf - xfl;
  int y0 = (int)yfl, x0 = (int)xfl;
  int y1 = y0 + 1, x1 = x0 + 1;
  if (y0 < 0) y0 = 0; if (x0 < 0) x0 = 0;
  if (y1 > 31) y1 = 31; if (x1 > 31) x1 = 31;
  const float* p = bm + (size_t)b * 1024;
  float v00 = p[y0 * 32 + x0], v01 = p[y0 * 32 + x1];
  float v10 = p[y1 * 32 + x0], v11 = p[y1 * 32 + x1];
  float v0 = v00 + fx * (v01 - v00);
  float v1 = v10 + fx * (v11 - v10);
  bw[idx] = v0 + fy * (v1 - v0);
}

// ---------------- gather x [B,C,H,W] f32 -> xw [nw*64][256] f16 -------------------
__global__ __launch_bounds__(256) void gather_x(const float* __restrict__ x,
                                                _Float16* __restrict__ xw) {
  const int c0 = blockIdx.x << 6;   // 0,64,128,192
  const int hh = blockIdx.y;        // 0..127
  const int b  = blockIdx.z;        // 0..7
  __shared__ float tile[64][133];
  const int tid = threadIdx.x;
  {
    const int cl = tid >> 7, p = tid & 127;
    const float* xp = x + ((size_t)(b * 256 + c0) * 128 + hh) * 128 + p;
#pragma unroll
    for (int i = 0; i < 32; ++i) {
      int c = i * 2 + cl;
      tile[c][p] = xp[(size_t)c * 16384];
    }
  }
  __syncthreads();
  const int w = tid >> 6, lane = tid & 63;
  const int hw = hh >> 3, ts = hh & 7;
#pragma unroll
  for (int i = 0; i < 32; ++i) {
    int pp = i * 4 + w;
    int row = ((b * 256 + hw * 16 + (pp >> 3)) << 6) + ts * 8 + (pp & 7);
    xw[(size_t)row * 256 + c0 + lane] = (_Float16)tile[lane][pp];
  }
}

// ---------------- scatter x2 [nw*64][256] f16 -> out [B,C,H,W] f32 ----------------
__global__ __launch_bounds__(256) void scatter_out(const _Float16* __restrict__ x2,
                                                   float* __restrict__ out) {
  const int c0 = blockIdx.x << 6;
  const int hh = blockIdx.y;
  const int b  = blockIdx.z;
  __shared__ float tile[64][133];
  const int tid = threadIdx.x;
  const int w = tid >> 6, lane = tid & 63;
  const int hw = hh >> 3, ts = hh & 7;
#pragma unroll
  for (int i = 0; i < 32; ++i) {
    int pp = i * 4 + w;
    int row = ((b * 256 + hw * 16 + (pp >> 3)) << 6) + ts * 8 + (pp & 7);
    tile[lane][pp] = (float)x2[(size_t)row * 256 + c0 + lane];
  }
  __syncthreads();
  const int cl = tid >> 7, p = tid & 127;
  float* op = out + ((size_t)(b * 256 + c0) * 128 + hh) * 128 + p;
#pragma unroll
  for (int i = 0; i < 32; ++i) {
    int c = i * 2 + cl;
    op[(size_t)c * 16384] = tile[c][p];
  }
}

// ---------------- f16 MFMA GEMM: C[M][N] = A[M][K] * BT[N][K]^T + bias ------------
// 128x128 tile, BK=32, 256 threads. T1 XCD-swizzle + KSWZ LDS.
// T3/T4-lite: 3-buffer, 2-deep prefetch, raw s_barrier + counted vmcnt(4)
// (never drains the in-flight prefetch; loads get ~2 K-steps to land).
template<int RELU>
__global__ __launch_bounds__(256) void gemm_f16(const _Float16* __restrict__ A,
    const _Float16* __restrict__ BT, const float* __restrict__ bias,
    _Float16* __restrict__ C, int M, int N, int K) {
  __shared__ _Float16 As[3][128 * 32];
  __shared__ _Float16 Bs[3][128 * 32];
  const int tid = threadIdx.x;
  const int gx = gridDim.x;
  int flat = blockIdx.y * gx + blockIdx.x;
  int nwg = gx * gridDim.y;
  int nb = (nwg & 7) ? flat : ((flat & 7) * (nwg >> 3) + (flat >> 3));
  const int m0 = (nb / gx) << 7;
  const int n0 = (nb % gx) << 7;
  const int w = tid >> 6, lane = tid & 63;
  const int wr = (w >> 1) << 6, wc = (w & 1) << 6;
  const int lr = lane & 15, lg = lane >> 4;
  f32x4 acc[4][4] = {};
  const int sr = tid >> 2, skk = ((tid & 3) << 3) ^ KSWZ(tid >> 2);
  const _Float16* Ag = A + (size_t)(m0 + sr) * K + skk;
  const _Float16* Bg = BT + (size_t)(n0 + sr) * K + skk;
  const size_t halfstep = (size_t)64 * K;
#define GSTAGE(bufi, k0) do { \
    gload_lds16(Ag + (k0),            &As[bufi][(size_t)tid * 8]); \
    gload_lds16(Ag + (k0) + halfstep, &As[bufi][(size_t)(256 + tid) * 8]); \
    gload_lds16(Bg + (k0),            &Bs[bufi][(size_t)tid * 8]); \
    gload_lds16(Bg + (k0) + halfstep, &Bs[bufi][(size_t)(256 + tid) * 8]); \
  } while (0)
  const int nsteps = K >> 5;                 // K/32, >= 8 for all our GEMMs
  GSTAGE(0, 0);
  GSTAGE(1, 32);
  int cur = 0;
  for (int t = 0; t < nsteps; ++t) {
    // wait for buf[cur]'s stage (issued 2 steps back); keep newest stage in flight
    if (t + 1 < nsteps) {
      asm volatile("s_waitcnt vmcnt(4)" ::: "memory");
    } else {
      asm volatile("s_waitcnt vmcnt(0)" ::: "memory");
    }
    __builtin_amdgcn_s_barrier();            // raw barrier: no vmcnt(0) drain
    half8 af[4], bf[4];
#pragma unroll
    for (int tt = 0; tt < 4; ++tt) {
      int rowA = wr + tt * 16 + lr;
      af[tt] = *(const half8*)&As[cur][rowA * 32 + ((lg * 8) ^ KSWZ(rowA))];
    }
#pragma unroll
    for (int tt = 0; tt < 4; ++tt) {
      int rowB = wc + tt * 16 + lr;
      bf[tt] = *(const half8*)&Bs[cur][rowB * 32 + ((lg * 8) ^ KSWZ(rowB))];
    }
#pragma unroll
    for (int i = 0; i < 4; ++i)
#pragma unroll
      for (int j = 0; j < 4; ++j)
        acc[i][j] = __builtin_amdgcn_mfma_f32_16x16x32_f16(af[i], bf[j], acc[i][j], 0, 0, 0);
    if (t + 2 < nsteps) {
      int nxt = cur + 2; if (nxt >= 3) nxt -= 3;
      GSTAGE(nxt, (t + 2) * 32);             // lands after this barrier -> no race
    }
    cur = (cur == 2) ? 0 : cur + 1;
  }
#undef GSTAGE
  float bv[4];
#pragma unroll
  for (int j = 0; j < 4; ++j) bv[j] = bias[n0 + wc + j * 16 + lr];
#pragma unroll
  for (int i = 0; i < 4; ++i) {
#pragma unroll
    for (int j = 0; j < 4; ++j) {
      int row = m0 + wr + i * 16 + lg * 4;
      int col = n0 + wc + j * 16 + lr;
      _Float16* cp = C + (size_t)row * N + col;
#pragma unroll
      for (int rr = 0; rr < 4; ++rr) {
        float v = acc[i][j][rr] + bv[j];
        if (RELU) v = fmaxf(v, 0.0f);
        cp[(size_t)rr * N] = (_Float16)v;
      }
    }
  }
}

// ---------------- MFMA attention: one block per window, 4 waves x 2 heads ---------
#define ATT_SWZ(row, col) (((row) << 6) + ((col) ^ (((row) & 7) << 3)))
__global__ __launch_bounds__(256, 3) void attn_mfma(const _Float16* __restrict__ qkv,
    const float* __restrict__ bw, _Float16* __restrict__ o) {
  const int wdw = blockIdx.x;          // window 0..2047
  const int w = threadIdx.x >> 6;      // wave 0..3
  const int lane = threadIdx.x & 63;
  const int lr = lane & 15, lg = lane >> 4;
  __shared__ _Float16 lds_p[4][64 * 64];   // P [64 q][64 k] f16, swizzled
  __shared__ _Float16 lds_v[4][32 * 64];   // V^T [32 d][64 j] f16, swizzled
  _Float16* Pb = lds_p[w];
  _Float16* Vt = lds_v[w];
  const size_t base = (size_t)wdw * 49152;   // 64*768 f16 elems
  f32x4 blv[4];
#pragma unroll
  for (int jt = 0; jt < 4; ++jt) {
    f32x4 bv = *(const f32x4*)&bw[wdw * 64 + jt * 16 + lg * 4];
    blv[jt] = bv * 0.0625f + 0.0625f;
  }
  const f32x4 zero4 = {0.f, 0.f, 0.f, 0.f};
#pragma unroll
  for (int hi = 0; hi < 2; ++hi) {
    const int h = w + hi * 4;
    const size_t qo = base + (size_t)h * 32;
    const _Float16* kp = qkv + qo + 256 + (size_t)lr * 768 + lg * 8;
    const _Float16* qp = qkv + qo +       (size_t)lr * 768 + lg * 8;
    half8 ak[4], bq[4];
#pragma unroll
    for (int t = 0; t < 4; ++t) {
      ak[t] = *(const half8*)(kp + (size_t)t * 16 * 768);
      bq[t] = *(const half8*)(qp + (size_t)t * 16 * 768);
    }
    const _Float16* vp = qkv + qo + 512 + (size_t)lane * 768;
#pragma unroll
    for (int e = 0; e < 4; ++e) {
      half8 vv = *(const half8*)(vp + e * 8);
#pragma unroll
      for (int d = 0; d < 8; ++d) Vt[ATT_SWZ(e * 8 + d, lane)] = vv[d];
    }
    f32x4 cst[4][4];
#pragma unroll
    for (int jt = 0; jt < 4; ++jt)
#pragma unroll
      for (int it = 0; it < 4; ++it)
        cst[jt][it] = __builtin_amdgcn_mfma_f32_16x16x32_f16(ak[jt], bq[it], zero4, 0, 0, 0);
#pragma unroll
    for (int it = 0; it < 4; ++it) {
      float m = -1e30f;
#pragma unroll
      for (int jt = 0; jt < 4; ++jt) {
        cst[jt][it] *= blv[jt];
        m = fmaxf(m, fmaxf(fmaxf(cst[jt][it][0], cst[jt][it][1]),
                           fmaxf(cst[jt][it][2], cst[jt][it][3])));
      }
      m = fmaxf(m, __shfl_xor(m, 16, 64));
      m = fmaxf(m, __shfl_xor(m, 32, 64));
      float s = 0.f;
#pragma unroll
      for (int jt = 0; jt < 4; ++jt)
#pragma unroll
        for (int r = 0; r < 4; ++r) {
          float e = __expf(cst[jt][it][r] - m);
          cst[jt][it][r] = e;
          s += e;
        }
      s += __shfl_xor(s, 16, 64);
      s += __shfl_xor(s, 32, 64);
      float inv = 1.0f / s;
#pragma unroll
      for (int jt = 0; jt < 4; ++jt) {
        half4 pv;
#pragma unroll
        for (int r = 0; r < 4; ++r) pv[r] = (_Float16)(cst[jt][it][r] * inv);
        *(half4*)&Pb[ATT_SWZ(it * 16 + lr, jt * 16 + lg * 4)] = pv;
      }
    }
    f32x4 co[4][2] = {};
#pragma unroll
    for (int ks = 0; ks < 2; ++ks) {
      half8 bv2[2], pa[4];
#pragma unroll
      for (int dt = 0; dt < 2; ++dt)
        bv2[dt] = *(const half8*)&Vt[ATT_SWZ(dt * 16 + lr, ks * 32 + lg * 8)];
#pragma unroll
      for (int it = 0; it < 4; ++it)
        pa[it] = *(const half8*)&Pb[ATT_SWZ(it * 16 + lr, ks * 32 + lg * 8)];
#pragma unroll
      for (int it = 0; it < 4; ++it)
#pragma unroll
        for (int dt = 0; dt < 2; ++dt)
          co[it][dt] = __builtin_amdgcn_mfma_f32_16x16x32_f16(pa[it], bv2[dt], co[it][dt], 0, 0, 0);
    }
#pragma unroll
    for (int it = 0; it < 4; ++it)
#pragma unroll
      for (int dt = 0; dt < 2; ++dt)
#pragma unroll
        for (int r = 0; r < 4; ++r) {
          int row = it * 16 + lg * 4 + r;
          o[((size_t)wdw * 64 + row) * 256 + h * 32 + dt * 16 + lr] =
              (_Float16)co[it][dt][r];
        }
  }
}

// ---------------- out = resid + LayerNorm(inp)*g + b  (wave per row, C=256) -------
__global__ __launch_bounds__(256) void ln_add(const _Float16* __restrict__ inp,
    const _Float16* __restrict__ res, const float* __restrict__ gg,
    const float* __restrict__ bb, _Float16* __restrict__ out) {
  const int w = threadIdx.x >> 6, lane = threadIdx.x & 63;
  const size_t row = (size_t)blockIdx.x * 4 + w;
  half4 v = ((const half4*)(inp + row * 256))[lane];
  float f0 = (float)v[0], f1 = (float)v[1], f2 = (float)v[2], f3 = (float)v[3];
  float s = f0 + f1 + f2 + f3;
  float s2 = f0*f0 + f1*f1 + f2*f2 + f3*f3;
#pragma unroll
  for (int m = 1; m < 64; m <<= 1) {
    s  += __shfl_xor(s, m, 64);
    s2 += __shfl_xor(s2, m, 64);
  }
  float mu = s * 0.00390625f;
  float var = s2 * 0.00390625f - mu * mu;
  float rs = rsqrtf(var + 1e-5f);
  f32x4 gv = *(const f32x4*)(gg + lane * 4);
  f32x4 bv = *(const f32x4*)(bb + lane * 4);
  half4 rv = ((const half4*)(res + row * 256))[lane];
  half4 ov;
  ov[0] = (_Float16)((f0 - mu) * rs * gv[0] + bv[0] + (float)rv[0]);
  ov[1] = (_Float16)((f1 - mu) * rs * gv[1] + bv[1] + (float)rv[1]);
  ov[2] = (_Float16)((f2 - mu) * rs * gv[2] + bv[2] + (float)rv[2]);
  ov[3] = (_Float16)((f3 - mu) * rs * gv[3] + bv[3] + (float)rv[3]);
  ((half4*)(out + row * 256))[lane] = ov;
}

__global__ __launch_bounds__(256) void sentinel(float* out, int n) {
  int i = blockIdx.x * 256 + threadIdx.x;
  if (i < n) out[i] = 12345.0f;
}

extern "C" void kernel_launch(void* const* d_in, const int* in_sizes, int n_in,
                              void* d_out, int out_size, void* d_ws, size_t ws_size,
                              hipStream_t stream) {
  const float* x      = (const float*)d_in[0];
  const float* blurm  = (const float*)d_in[1];
  const float* qkv_w  = (const float*)d_in[2];
  const float* qkv_b  = (const float*)d_in[3];
  const float* proj_w = (const float*)d_in[4];
  const float* proj_b = (const float*)d_in[5];
  const float* ff1_w  = (const float*)d_in[6];
  const float* ff1_b  = (const float*)d_in[7];
  const float* ff2_w  = (const float*)d_in[8];
  const float* ff2_b  = (const float*)d_in[9];
  const float* n1_g   = (const float*)d_in[10];
  const float* n1_b   = (const float*)d_in[11];
  const float* n2_g   = (const float*)d_in[12];
  const float* n2_b   = (const float*)d_in[13];
  float* out = (float*)d_out;

  char* ws = (char*)d_ws;
  constexpr size_t OFF_RA  = 0;                          // qkv f16; later ff1-out f16 (268MB, spans RA+XW+AO)
  constexpr size_t OFF_XW  = 201326592ull;               // xw f16, later x2 f16
  constexpr size_t OFF_AO  = OFF_XW + 67108864ull;       // attn out f16
  constexpr size_t OFF_RC  = OFF_AO + 67108864ull;       // proj out / ff2 out f16
  constexpr size_t OFF_X1  = OFF_RC + 67108864ull;       // x1 f16
  constexpr size_t OFF_QW  = OFF_X1 + 67108864ull;
  constexpr size_t OFF_PW  = OFF_QW + 393216ull;
  constexpr size_t OFF_F1W = OFF_PW + 131072ull;
  constexpr size_t OFF_F2W = OFF_F1W + 524288ull;
  constexpr size_t OFF_BL  = OFF_F2W + 524288ull;
  constexpr size_t NEED    = OFF_BL + 524288ull;
  if (ws_size < NEED) {
    sentinel<<<(out_size + 255) / 256, 256, 0, stream>>>(out, out_size);
    return;
  }
  _Float16* RA   = (_Float16*)(ws + OFF_RA);
  _Float16* F    = (_Float16*)(ws + OFF_RA);   // ff1 out [131072x1024] f16 = 268MB (RA/XW/AO dead)
  _Float16* xw_h = (_Float16*)(ws + OFF_XW);
  _Float16* ao   = (_Float16*)(ws + OFF_AO);
  _Float16* rc   = (_Float16*)(ws + OFF_RC);
  _Float16* x1h  = (_Float16*)(ws + OFF_X1);
  _Float16* qwT  = (_Float16*)(ws + OFF_QW);
  _Float16* pwT  = (_Float16*)(ws + OFF_PW);
  _Float16* f1wT = (_Float16*)(ws + OFF_F1W);
  _Float16* f2wT = (_Float16*)(ws + OFF_F2W);
  float* blurw   = (float*)(ws + OFF_BL);

  wtrans<<<768, 256, 0, stream>>>(qkv_w, qwT, 256, 768);
  wtrans<<<256, 256, 0, stream>>>(proj_w, pwT, 256, 256);
  wtrans<<<1024, 256, 0, stream>>>(ff1_w, f1wT, 256, 1024);
  wtrans<<<1024, 256, 0, stream>>>(ff2_w, f2wT, 1024, 256);
  blur_prep<<<512, 256, 0, stream>>>(blurm, blurw);
  gather_x<<<dim3(4, 128, 8), 256, 0, stream>>>(x, xw_h);

  // qkv = xw @ qkv_w + b          [131072, 768]
  gemm_f16<0><<<dim3(6, 1024), 256, 0, stream>>>(xw_h, qwT, qkv_b, RA, 131072, 768, 256);
  // windowed blur-modulated MFMA attention -> [131072, 256]
  attn_mfma<<<2048, 256, 0, stream>>>(RA, blurw, ao);
  // proj
  gemm_f16<0><<<dim3(2, 1024), 256, 0, stream>>>(ao, pwT, proj_b, rc, 131072, 256, 256);
  // x1 = xw + LN1(proj)
  ln_add<<<32768, 256, 0, stream>>>(rc, xw_h, n1_g, n1_b, x1h);
  // ff single-pass: F = relu(x1 @ ff1_w + b1); rc = F @ ff2_w + b2
  gemm_f16<1><<<dim3(8, 1024), 256, 0, stream>>>(x1h, f1wT, ff1_b, F, 131072, 1024, 256);
  gemm_f16<0><<<dim3(2, 1024), 256, 0, stream>>>(F, f2wT, ff2_b, rc, 131072, 256, 1024);
  // x2 = x1 + LN2(ff2)  (write into xw region; F dead now)
  ln_add<<<32768, 256, 0, stream>>>(rc, x1h, n2_g, n2_b, xw_h);
  scatter_out<<<dim3(4, 128, 8), 256, 0, stream>>>(xw_h, out);
}

// Round 14
// 588.302 us; speedup vs baseline: 1.3409x; 1.0622x over previous
//
#include <hip/hip_runtime.h>
#include <hip/hip_bf16.h>
#include <cstdint>

typedef _Float16 half8 __attribute__((ext_vector_type(8)));
typedef _Float16 half4 __attribute__((ext_vector_type(4)));
typedef float f32x4 __attribute__((ext_vector_type(4)));

__device__ __forceinline__ void gload_lds16(const _Float16* g, _Float16* l) {
  __builtin_amdgcn_global_load_lds(
      (const __attribute__((address_space(1))) void*)g,
      (__attribute__((address_space(3))) void*)l, 16, 0, 0);
}

// LDS col swizzle for 32-elem (64 B) rows, 16 B granular, involution.
#define KSWZ(r) ((((r) >> 1) & 3) << 3)

// ------- merged weight transposes: WT[n][k] = W[k][n], f32 -> f16 (one launch) ----
__global__ __launch_bounds__(256) void wtrans_all(
    const float* __restrict__ qkv_w, const float* __restrict__ proj_w,
    const float* __restrict__ ff1_w, const float* __restrict__ ff2_w,
    _Float16* __restrict__ qwT, _Float16* __restrict__ pwT,
    _Float16* __restrict__ f1T, _Float16* __restrict__ f2T) {
  const int b = blockIdx.x;
  const float* W; _Float16* WT; int K, N, idx;
  if (b < 768)       { W = qkv_w;  WT = qwT; K = 256;  N = 768;  idx = b * 256 + threadIdx.x; }
  else if (b < 1024) { W = proj_w; WT = pwT; K = 256;  N = 256;  idx = (b - 768) * 256 + threadIdx.x; }
  else if (b < 2048) { W = ff1_w;  WT = f1T; K = 256;  N = 1024; idx = (b - 1024) * 256 + threadIdx.x; }
  else               { W = ff2_w;  WT = f2T; K = 1024; N = 256;  idx = (b - 2048) * 256 + threadIdx.x; }
  int k = idx / N, n = idx - k * N;
  WT[(size_t)n * K + k] = (_Float16)W[idx];
}

// ---------------- blur bilinear upsample 32x32 -> 128x128, windowed [nw][64] ------
__global__ __launch_bounds__(256) void blur_prep(const float* __restrict__ bm,
                                                 float* __restrict__ bw) {
  int idx = blockIdx.x * 256 + threadIdx.x;   // 0..131071
  int wi = idx >> 6, t = idx & 63;
  int b = wi >> 8, wid = wi & 255;
  int hw = wid >> 4, ww = wid & 15;
  int hh = hw * 8 + (t >> 3), www = ww * 8 + (t & 7);
  float yf = (hh + 0.5f) * 0.25f - 0.5f;
  float xf = (www + 0.5f) * 0.25f - 0.5f;
  float yfl = floorf(yf), xfl = floorf(xf);
  float fy = yf - yfl, fx = xf - xfl;
  int y0 = (int)yfl, x0 = (int)xfl;
  int y1 = y0 + 1, x1 = x0 + 1;
  if (y0 < 0) y0 = 0; if (x0 < 0) x0 = 0;
  if (y1 > 31) y1 = 31; if (x1 > 31) x1 = 31;
  const float* p = bm + (size_t)b * 1024;
  float v00 = p[y0 * 32 + x0], v01 = p[y0 * 32 + x1];
  float v10 = p[y1 * 32 + x0], v11 = p[y1 * 32 + x1];
  float v0 = v00 + fx * (v01 - v00);
  float v1 = v10 + fx * (v11 - v10);
  bw[idx] = v0 + fy * (v1 - v0);
}

// ---------------- gather x [B,C,H,W] f32 -> xw [nw*64][256] f16 -------------------
__global__ __launch_bounds__(256) void gather_x(const float* __restrict__ x,
                                                _Float16* __restrict__ xw) {
  const int c0 = blockIdx.x << 6;   // 0,64,128,192
  const int hh = blockIdx.y;        // 0..127
  const int b  = blockIdx.z;        // 0..7
  __shared__ float tile[64][133];
  const int tid = threadIdx.x;
  {
    const int cl = tid >> 7, p = tid & 127;
    const float* xp = x + ((size_t)(b * 256 + c0) * 128 + hh) * 128 + p;
#pragma unroll
    for (int i = 0; i < 32; ++i) {
      int c = i * 2 + cl;
      tile[c][p] = xp[(size_t)c * 16384];
    }
  }
  __syncthreads();
  const int w = tid >> 6, lane = tid & 63;
  const int hw = hh >> 3, ts = hh & 7;
#pragma unroll
  for (int i = 0; i < 32; ++i) {
    int pp = i * 4 + w;
    int row = ((b * 256 + hw * 16 + (pp >> 3)) << 6) + ts * 8 + (pp & 7);
    xw[(size_t)row * 256 + c0 + lane] = (_Float16)tile[lane][pp];
  }
}

// ---------------- scatter x2 [nw*64][256] f16 -> out [B,C,H,W] f32 ----------------
__global__ __launch_bounds__(256) void scatter_out(const _Float16* __restrict__ x2,
                                                   float* __restrict__ out) {
  const int c0 = blockIdx.x << 6;
  const int hh = blockIdx.y;
  const int b  = blockIdx.z;
  __shared__ float tile[64][133];
  const int tid = threadIdx.x;
  const int w = tid >> 6, lane = tid & 63;
  const int hw = hh >> 3, ts = hh & 7;
#pragma unroll
  for (int i = 0; i < 32; ++i) {
    int pp = i * 4 + w;
    int row = ((b * 256 + hw * 16 + (pp >> 3)) << 6) + ts * 8 + (pp & 7);
    tile[lane][pp] = (float)x2[(size_t)row * 256 + c0 + lane];
  }
  __syncthreads();
  const int cl = tid >> 7, p = tid & 127;
  float* op = out + ((size_t)(b * 256 + c0) * 128 + hh) * 128 + p;
#pragma unroll
  for (int i = 0; i < 32; ++i) {
    int c = i * 2 + cl;
    op[(size_t)c * 16384] = tile[c][p];
  }
}

// ---------------- f16 MFMA GEMM: C[M][N] = A[M][K] * BT[N][K]^T + bias ------------
// 128x128 tile, BK=32, 256 threads. T1 XCD-swizzle + KSWZ LDS.
// T3/T4-lite: 3-buffer, 2-deep prefetch, raw s_barrier + counted vmcnt(4)
// (never drains the in-flight prefetch; loads get ~2 K-steps to land).
template<int RELU>
__global__ __launch_bounds__(256) void gemm_f16(const _Float16* __restrict__ A,
    const _Float16* __restrict__ BT, const float* __restrict__ bias,
    _Float16* __restrict__ C, int M, int N, int K) {
  __shared__ _Float16 As[3][128 * 32];
  __shared__ _Float16 Bs[3][128 * 32];
  const int tid = threadIdx.x;
  const int gx = gridDim.x;
  int flat = blockIdx.y * gx + blockIdx.x;
  int nwg = gx * gridDim.y;
  int nb = (nwg & 7) ? flat : ((flat & 7) * (nwg >> 3) + (flat >> 3));
  const int m0 = (nb / gx) << 7;
  const int n0 = (nb % gx) << 7;
  const int w = tid >> 6, lane = tid & 63;
  const int wr = (w >> 1) << 6, wc = (w & 1) << 6;
  const int lr = lane & 15, lg = lane >> 4;
  f32x4 acc[4][4] = {};
  const int sr = tid >> 2, skk = ((tid & 3) << 3) ^ KSWZ(tid >> 2);
  const _Float16* Ag = A + (size_t)(m0 + sr) * K + skk;
  const _Float16* Bg = BT + (size_t)(n0 + sr) * K + skk;
  const size_t halfstep = (size_t)64 * K;
#define GSTAGE(bufi, k0) do { \
    gload_lds16(Ag + (k0),            &As[bufi][(size_t)tid * 8]); \
    gload_lds16(Ag + (k0) + halfstep, &As[bufi][(size_t)(256 + tid) * 8]); \
    gload_lds16(Bg + (k0),            &Bs[bufi][(size_t)tid * 8]); \
    gload_lds16(Bg + (k0) + halfstep, &Bs[bufi][(size_t)(256 + tid) * 8]); \
  } while (0)
  const int nsteps = K >> 5;                 // K/32, >= 8 for all our GEMMs
  GSTAGE(0, 0);
  GSTAGE(1, 32);
  int cur = 0;
  for (int t = 0; t < nsteps; ++t) {
    // wait for buf[cur]'s stage (issued 2 steps back); keep newest stage in flight
    if (t + 1 < nsteps) {
      asm volatile("s_waitcnt vmcnt(4)" ::: "memory");
    } else {
      asm volatile("s_waitcnt vmcnt(0)" ::: "memory");
    }
    __builtin_amdgcn_s_barrier();            // raw barrier: no vmcnt(0) drain
    half8 af[4], bf[4];
#pragma unroll
    for (int tt = 0; tt < 4; ++tt) {
      int rowA = wr + tt * 16 + lr;
      af[tt] = *(const half8*)&As[cur][rowA * 32 + ((lg * 8) ^ KSWZ(rowA))];
    }
#pragma unroll
    for (int tt = 0; tt < 4; ++tt) {
      int rowB = wc + tt * 16 + lr;
      bf[tt] = *(const half8*)&Bs[cur][rowB * 32 + ((lg * 8) ^ KSWZ(rowB))];
    }
#pragma unroll
    for (int i = 0; i < 4; ++i)
#pragma unroll
      for (int j = 0; j < 4; ++j)
        acc[i][j] = __builtin_amdgcn_mfma_f32_16x16x32_f16(af[i], bf[j], acc[i][j], 0, 0, 0);
    if (t + 2 < nsteps) {
      int nxt = cur + 2; if (nxt >= 3) nxt -= 3;
      GSTAGE(nxt, (t + 2) * 32);             // lands after this barrier -> no race
    }
    cur = (cur == 2) ? 0 : cur + 1;
  }
#undef GSTAGE
  float bv[4];
#pragma unroll
  for (int j = 0; j < 4; ++j) bv[j] = bias[n0 + wc + j * 16 + lr];
#pragma unroll
  for (int i = 0; i < 4; ++i) {
#pragma unroll
    for (int j = 0; j < 4; ++j) {
      int row = m0 + wr + i * 16 + lg * 4;
      int col = n0 + wc + j * 16 + lr;
      _Float16* cp = C + (size_t)row * N + col;
#pragma unroll
      for (int rr = 0; rr < 4; ++rr) {
        float v = acc[i][j][rr] + bv[j];
        if (RELU) v = fmaxf(v, 0.0f);
        cp[(size_t)rr * N] = (_Float16)v;
      }
    }
  }
}

// ---------------- MFMA attention: one block per window, 4 waves x 2 heads ---------
// T5: s_setprio(1) around MFMA clusters (independent blocks at different phases).
#define ATT_SWZ(row, col) (((row) << 6) + ((col) ^ (((row) & 7) << 3)))
__global__ __launch_bounds__(256, 3) void attn_mfma(const _Float16* __restrict__ qkv,
    const float* __restrict__ bw, _Float16* __restrict__ o) {
  const int wdw = blockIdx.x;          // window 0..2047
  const int w = threadIdx.x >> 6;      // wave 0..3
  const int lane = threadIdx.x & 63;
  const int lr = lane & 15, lg = lane >> 4;
  __shared__ _Float16 lds_p[4][64 * 64];   // P [64 q][64 k] f16, swizzled
  __shared__ _Float16 lds_v[4][32 * 64];   // V^T [32 d][64 j] f16, swizzled
  _Float16* Pb = lds_p[w];
  _Float16* Vt = lds_v[w];
  const size_t base = (size_t)wdw * 49152;   // 64*768 f16 elems
  f32x4 blv[4];
#pragma unroll
  for (int jt = 0; jt < 4; ++jt) {
    f32x4 bv = *(const f32x4*)&bw[wdw * 64 + jt * 16 + lg * 4];
    blv[jt] = bv * 0.0625f + 0.0625f;
  }
  const f32x4 zero4 = {0.f, 0.f, 0.f, 0.f};
#pragma unroll
  for (int hi = 0; hi < 2; ++hi) {
    const int h = w + hi * 4;
    const size_t qo = base + (size_t)h * 32;
    const _Float16* kp = qkv + qo + 256 + (size_t)lr * 768 + lg * 8;
    const _Float16* qp = qkv + qo +       (size_t)lr * 768 + lg * 8;
    half8 ak[4], bq[4];
#pragma unroll
    for (int t = 0; t < 4; ++t) {
      ak[t] = *(const half8*)(kp + (size_t)t * 16 * 768);
      bq[t] = *(const half8*)(qp + (size_t)t * 16 * 768);
    }
    const _Float16* vp = qkv + qo + 512 + (size_t)lane * 768;
#pragma unroll
    for (int e = 0; e < 4; ++e) {
      half8 vv = *(const half8*)(vp + e * 8);
#pragma unroll
      for (int d = 0; d < 8; ++d) Vt[ATT_SWZ(e * 8 + d, lane)] = vv[d];
    }
    f32x4 cst[4][4];
    __builtin_amdgcn_s_setprio(1);
#pragma unroll
    for (int jt = 0; jt < 4; ++jt)
#pragma unroll
      for (int it = 0; it < 4; ++it)
        cst[jt][it] = __builtin_amdgcn_mfma_f32_16x16x32_f16(ak[jt], bq[it], zero4, 0, 0, 0);
    __builtin_amdgcn_s_setprio(0);
#pragma unroll
    for (int it = 0; it < 4; ++it) {
      float m = -1e30f;
#pragma unroll
      for (int jt = 0; jt < 4; ++jt) {
        cst[jt][it] *= blv[jt];
        m = fmaxf(m, fmaxf(fmaxf(cst[jt][it][0], cst[jt][it][1]),
                           fmaxf(cst[jt][it][2], cst[jt][it][3])));
      }
      m = fmaxf(m, __shfl_xor(m, 16, 64));
      m = fmaxf(m, __shfl_xor(m, 32, 64));
      float s = 0.f;
#pragma unroll
      for (int jt = 0; jt < 4; ++jt)
#pragma unroll
        for (int r = 0; r < 4; ++r) {
          float e = __expf(cst[jt][it][r] - m);
          cst[jt][it][r] = e;
          s += e;
        }
      s += __shfl_xor(s, 16, 64);
      s += __shfl_xor(s, 32, 64);
      float inv = 1.0f / s;
#pragma unroll
      for (int jt = 0; jt < 4; ++jt) {
        half4 pv;
#pragma unroll
        for (int r = 0; r < 4; ++r) pv[r] = (_Float16)(cst[jt][it][r] * inv);
        *(half4*)&Pb[ATT_SWZ(it * 16 + lr, jt * 16 + lg * 4)] = pv;
      }
    }
    f32x4 co[4][2] = {};
#pragma unroll
    for (int ks = 0; ks < 2; ++ks) {
      half8 bv2[2], pa[4];
#pragma unroll
      for (int dt = 0; dt < 2; ++dt)
        bv2[dt] = *(const half8*)&Vt[ATT_SWZ(dt * 16 + lr, ks * 32 + lg * 8)];
#pragma unroll
      for (int it = 0; it < 4; ++it)
        pa[it] = *(const half8*)&Pb[ATT_SWZ(it * 16 + lr, ks * 32 + lg * 8)];
      __builtin_amdgcn_s_setprio(1);
#pragma unroll
      for (int it = 0; it < 4; ++it)
#pragma unroll
        for (int dt = 0; dt < 2; ++dt)
          co[it][dt] = __builtin_amdgcn_mfma_f32_16x16x32_f16(pa[it], bv2[dt], co[it][dt], 0, 0, 0);
      __builtin_amdgcn_s_setprio(0);
    }
#pragma unroll
    for (int it = 0; it < 4; ++it)
#pragma unroll
      for (int dt = 0; dt < 2; ++dt)
#pragma unroll
        for (int r = 0; r < 4; ++r) {
          int row = it * 16 + lg * 4 + r;
          o[((size_t)wdw * 64 + row) * 256 + h * 32 + dt * 16 + lr] =
              (_Float16)co[it][dt][r];
        }
  }
}

// ---------------- out = resid + LayerNorm(inp)*g + b  (wave per row, C=256) -------
__global__ __launch_bounds__(256) void ln_add(const _Float16* __restrict__ inp,
    const _Float16* __restrict__ res, const float* __restrict__ gg,
    const float* __restrict__ bb, _Float16* __restrict__ out) {
  const int w = threadIdx.x >> 6, lane = threadIdx.x & 63;
  const size_t row = (size_t)blockIdx.x * 4 + w;
  half4 v = ((const half4*)(inp + row * 256))[lane];
  float f0 = (float)v[0], f1 = (float)v[1], f2 = (float)v[2], f3 = (float)v[3];
  float s = f0 + f1 + f2 + f3;
  float s2 = f0*f0 + f1*f1 + f2*f2 + f3*f3;
#pragma unroll
  for (int m = 1; m < 64; m <<= 1) {
    s  += __shfl_xor(s, m, 64);
    s2 += __shfl_xor(s2, m, 64);
  }
  float mu = s * 0.00390625f;
  float var = s2 * 0.00390625f - mu * mu;
  float rs = rsqrtf(var + 1e-5f);
  f32x4 gv = *(const f32x4*)(gg + lane * 4);
  f32x4 bv = *(const f32x4*)(bb + lane * 4);
  half4 rv = ((const half4*)(res + row * 256))[lane];
  half4 ov;
  ov[0] = (_Float16)((f0 - mu) * rs * gv[0] + bv[0] + (float)rv[0]);
  ov[1] = (_Float16)((f1 - mu) * rs * gv[1] + bv[1] + (float)rv[1]);
  ov[2] = (_Float16)((f2 - mu) * rs * gv[2] + bv[2] + (float)rv[2]);
  ov[3] = (_Float16)((f3 - mu) * rs * gv[3] + bv[3] + (float)rv[3]);
  ((half4*)(out + row * 256))[lane] = ov;
}

__global__ __launch_bounds__(256) void sentinel(float* out, int n) {
  int i = blockIdx.x * 256 + threadIdx.x;
  if (i < n) out[i] = 12345.0f;
}

extern "C" void kernel_launch(void* const* d_in, const int* in_sizes, int n_in,
                              void* d_out, int out_size, void* d_ws, size_t ws_size,
                              hipStream_t stream) {
  const float* x      = (const float*)d_in[0];
  const float* blurm  = (const float*)d_in[1];
  const float* qkv_w  = (const float*)d_in[2];
  const float* qkv_b  = (const float*)d_in[3];
  const float* proj_w = (const float*)d_in[4];
  const float* proj_b = (const float*)d_in[5];
  const float* ff1_w  = (const float*)d_in[6];
  const float* ff1_b  = (const float*)d_in[7];
  const float* ff2_w  = (const float*)d_in[8];
  const float* ff2_b  = (const float*)d_in[9];
  const float* n1_g   = (const float*)d_in[10];
  const float* n1_b   = (const float*)d_in[11];
  const float* n2_g   = (const float*)d_in[12];
  const float* n2_b   = (const float*)d_in[13];
  float* out = (float*)d_out;

  char* ws = (char*)d_ws;
  constexpr size_t OFF_RA  = 0;                          // qkv f16 / ff1-half f16
  constexpr size_t OFF_XW  = 201326592ull;               // xw f16, later x2 f16
  constexpr size_t OFF_AO  = OFF_XW + 67108864ull;       // attn out f16
  constexpr size_t OFF_RC  = OFF_AO + 67108864ull;       // proj out / ff2 out f16
  constexpr size_t OFF_X1  = OFF_RC + 67108864ull;       // x1 f16
  constexpr size_t OFF_QW  = OFF_X1 + 67108864ull;
  constexpr size_t OFF_PW  = OFF_QW + 393216ull;
  constexpr size_t OFF_F1W = OFF_PW + 131072ull;
  constexpr size_t OFF_F2W = OFF_F1W + 524288ull;
  constexpr size_t OFF_BL  = OFF_F2W + 524288ull;
  constexpr size_t NEED    = OFF_BL + 524288ull;
  if (ws_size < NEED) {
    sentinel<<<(out_size + 255) / 256, 256, 0, stream>>>(out, out_size);
    return;
  }
  _Float16* RA   = (_Float16*)(ws + OFF_RA);
  _Float16* xw_h = (_Float16*)(ws + OFF_XW);
  _Float16* ao   = (_Float16*)(ws + OFF_AO);
  _Float16* rc   = (_Float16*)(ws + OFF_RC);
  _Float16* x1h  = (_Float16*)(ws + OFF_X1);
  _Float16* qwT  = (_Float16*)(ws + OFF_QW);
  _Float16* pwT  = (_Float16*)(ws + OFF_PW);
  _Float16* f1wT = (_Float16*)(ws + OFF_F1W);
  _Float16* f2wT = (_Float16*)(ws + OFF_F2W);
  float* blurw   = (float*)(ws + OFF_BL);

  wtrans_all<<<3072, 256, 0, stream>>>(qkv_w, proj_w, ff1_w, ff2_w, qwT, pwT, f1wT, f2wT);
  blur_prep<<<512, 256, 0, stream>>>(blurm, blurw);
  gather_x<<<dim3(4, 128, 8), 256, 0, stream>>>(x, xw_h);

  // qkv = xw @ qkv_w + b          [131072, 768]
  gemm_f16<0><<<dim3(6, 1024), 256, 0, stream>>>(xw_h, qwT, qkv_b, RA, 131072, 768, 256);
  // windowed blur-modulated MFMA attention -> [131072, 256]
  attn_mfma<<<2048, 256, 0, stream>>>(RA, blurw, ao);
  // proj
  gemm_f16<0><<<dim3(2, 1024), 256, 0, stream>>>(ao, pwT, proj_b, rc, 131072, 256, 256);
  // x1 = xw + LN1(proj)
  ln_add<<<32768, 256, 0, stream>>>(rc, xw_h, n1_g, n1_b, x1h);
  // ff in two M-halves (measured best)
  for (int ch = 0; ch < 2; ++ch) {
    const size_t off = (size_t)ch * 65536 * 256;
    gemm_f16<1><<<dim3(8, 512), 256, 0, stream>>>(x1h + off, f1wT, ff1_b,
                                                  RA, 65536, 1024, 256);
    gemm_f16<0><<<dim3(2, 512), 256, 0, stream>>>(RA, f2wT, ff2_b,
                                                  rc + off, 65536, 256, 1024);
  }
  // x2 = x1 + LN2(ff2)  (write into xw region; xw dead after LN1)
  ln_add<<<32768, 256, 0, stream>>>(rc, x1h, n2_g, n2_b, xw_h);
  scatter_out<<<dim3(4, 128, 8), 256, 0, stream>>>(xw_h, out);
}

// Round 15
// 586.583 us; speedup vs baseline: 1.3448x; 1.0029x over previous
//
#include <hip/hip_runtime.h>
#include <hip/hip_bf16.h>
#include <cstdint>

typedef _Float16 half8 __attribute__((ext_vector_type(8)));
typedef _Float16 half4 __attribute__((ext_vector_type(4)));
typedef float f32x4 __attribute__((ext_vector_type(4)));

__device__ __forceinline__ void gload_lds16(const _Float16* g, _Float16* l) {
  __builtin_amdgcn_global_load_lds(
      (const __attribute__((address_space(1))) void*)g,
      (__attribute__((address_space(3))) void*)l, 16, 0, 0);
}

// LDS col swizzle for 32-elem (64 B) rows, 16 B granular, involution.
#define KSWZ(r) ((((r) >> 1) & 3) << 3)

// ------- merged weight transposes: WT[n][k] = W[k][n], f32 -> f16 (one launch) ----
__global__ __launch_bounds__(256) void wtrans_all(
    const float* __restrict__ qkv_w, const float* __restrict__ proj_w,
    const float* __restrict__ ff1_w, const float* __restrict__ ff2_w,
    _Float16* __restrict__ qwT, _Float16* __restrict__ pwT,
    _Float16* __restrict__ f1T, _Float16* __restrict__ f2T) {
  const int b = blockIdx.x;
  const float* W; _Float16* WT; int K, N, idx;
  if (b < 768)       { W = qkv_w;  WT = qwT; K = 256;  N = 768;  idx = b * 256 + threadIdx.x; }
  else if (b < 1024) { W = proj_w; WT = pwT; K = 256;  N = 256;  idx = (b - 768) * 256 + threadIdx.x; }
  else if (b < 2048) { W = ff1_w;  WT = f1T; K = 256;  N = 1024; idx = (b - 1024) * 256 + threadIdx.x; }
  else               { W = ff2_w;  WT = f2T; K = 1024; N = 256;  idx = (b - 2048) * 256 + threadIdx.x; }
  int k = idx / N, n = idx - k * N;
  WT[(size_t)n * K + k] = (_Float16)W[idx];
}

// ---------------- blur bilinear upsample 32x32 -> 128x128, windowed [nw][64] ------
__global__ __launch_bounds__(256) void blur_prep(const float* __restrict__ bm,
                                                 float* __restrict__ bw) {
  int idx = blockIdx.x * 256 + threadIdx.x;   // 0..131071
  int wi = idx >> 6, t = idx & 63;
  int b = wi >> 8, wid = wi & 255;
  int hw = wid >> 4, ww = wid & 15;
  int hh = hw * 8 + (t >> 3), www = ww * 8 + (t & 7);
  float yf = (hh + 0.5f) * 0.25f - 0.5f;
  float xf = (www + 0.5f) * 0.25f - 0.5f;
  float yfl = floorf(yf), xfl = floorf(xf);
  float fy = yf - yfl, fx = xf - xfl;
  int y0 = (int)yfl, x0 = (int)xfl;
  int y1 = y0 + 1, x1 = x0 + 1;
  if (y0 < 0) y0 = 0; if (x0 < 0) x0 = 0;
  if (y1 > 31) y1 = 31; if (x1 > 31) x1 = 31;
  const float* p = bm + (size_t)b * 1024;
  float v00 = p[y0 * 32 + x0], v01 = p[y0 * 32 + x1];
  float v10 = p[y1 * 32 + x0], v11 = p[y1 * 32 + x1];
  float v0 = v00 + fx * (v01 - v00);
  float v1 = v10 + fx * (v11 - v10);
  bw[idx] = v0 + fy * (v1 - v0);
}

// ---------------- gather x [B,C,H,W] f32 -> xw [nw*64][256] f16 -------------------
__global__ __launch_bounds__(256) void gather_x(const float* __restrict__ x,
                                                _Float16* __restrict__ xw) {
  const int c0 = blockIdx.x << 6;   // 0,64,128,192
  const int hh = blockIdx.y;        // 0..127
  const int b  = blockIdx.z;        // 0..7
  __shared__ float tile[64][133];
  const int tid = threadIdx.x;
  {
    const int cl = tid >> 7, p = tid & 127;
    const float* xp = x + ((size_t)(b * 256 + c0) * 128 + hh) * 128 + p;
#pragma unroll
    for (int i = 0; i < 32; ++i) {
      int c = i * 2 + cl;
      tile[c][p] = xp[(size_t)c * 16384];
    }
  }
  __syncthreads();
  const int w = tid >> 6, lane = tid & 63;
  const int hw = hh >> 3, ts = hh & 7;
#pragma unroll
  for (int i = 0; i < 32; ++i) {
    int pp = i * 4 + w;
    int row = ((b * 256 + hw * 16 + (pp >> 3)) << 6) + ts * 8 + (pp & 7);
    xw[(size_t)row * 256 + c0 + lane] = (_Float16)tile[lane][pp];
  }
}

// ------- fused: x2 = x1 + LN2(rc)  ->  window-reverse  ->  out [B,C,H,W] f32 ------
// One block per (hh, b). Phase 1: wave reads token rows coalesced, LN via shfl,
// writes f16 into transposed LDS tile [128 px][258] (row stride 129 dwords:
// phase-1 ds_write_b64 contiguous; phase-2 lanes hit distinct banks, 2/bank=free).
__global__ __launch_bounds__(256) void ln_scatter(const _Float16* __restrict__ rc,
    const _Float16* __restrict__ x1, const float* __restrict__ gg,
    const float* __restrict__ bb, float* __restrict__ out) {
  const int hh = blockIdx.x;   // 0..127
  const int b  = blockIdx.y;   // 0..7
  __shared__ _Float16 tile[128][258];
  const int w = threadIdx.x >> 6, lane = threadIdx.x & 63;
  const int hw = hh >> 3, ts = hh & 7;
  f32x4 gv = *(const f32x4*)(gg + lane * 4);
  f32x4 bv = *(const f32x4*)(bb + lane * 4);
#pragma unroll
  for (int i = 0; i < 32; ++i) {
    const int pp = w * 32 + i;   // pixel x 0..127
    const size_t row = ((size_t)(b * 256 + hw * 16 + (pp >> 3)) << 6) + ts * 8 + (pp & 7);
    half4 v  = ((const half4*)(rc + row * 256))[lane];
    half4 rv = ((const half4*)(x1 + row * 256))[lane];
    float f0 = (float)v[0], f1 = (float)v[1], f2 = (float)v[2], f3 = (float)v[3];
    float s = f0 + f1 + f2 + f3;
    float s2 = f0*f0 + f1*f1 + f2*f2 + f3*f3;
#pragma unroll
    for (int m = 1; m < 64; m <<= 1) {
      s  += __shfl_xor(s, m, 64);
      s2 += __shfl_xor(s2, m, 64);
    }
    float mu = s * 0.00390625f;
    float var = s2 * 0.00390625f - mu * mu;
    float rs = rsqrtf(var + 1e-5f);
    half4 ov;
    ov[0] = (_Float16)((f0 - mu) * rs * gv[0] + bv[0] + (float)rv[0]);
    ov[1] = (_Float16)((f1 - mu) * rs * gv[1] + bv[1] + (float)rv[1]);
    ov[2] = (_Float16)((f2 - mu) * rs * gv[2] + bv[2] + (float)rv[2]);
    ov[3] = (_Float16)((f3 - mu) * rs * gv[3] + bv[3] + (float)rv[3]);
    *(half4*)&tile[pp][lane * 4] = ov;
  }
  __syncthreads();
  const int cl = threadIdx.x >> 7, p = threadIdx.x & 127;
  float* op = out + ((size_t)(b * 256) * 128 + hh) * 128 + p;
#pragma unroll
  for (int i = 0; i < 128; ++i) {
    int c = i * 2 + cl;
    op[(size_t)c * 16384] = (float)tile[p][c];
  }
}

// ---------------- f16 MFMA GEMM: C[M][N] = A[M][K] * BT[N][K]^T + bias ------------
// 128x128 tile, BK=32, 256 threads. T1 XCD-swizzle + KSWZ LDS.
// T3/T4-lite: 3-buffer, 2-deep prefetch, raw s_barrier + counted vmcnt(4)
// (never drains the in-flight prefetch; loads get ~2 K-steps to land).
template<int RELU>
__global__ __launch_bounds__(256) void gemm_f16(const _Float16* __restrict__ A,
    const _Float16* __restrict__ BT, const float* __restrict__ bias,
    _Float16* __restrict__ C, int M, int N, int K) {
  __shared__ _Float16 As[3][128 * 32];
  __shared__ _Float16 Bs[3][128 * 32];
  const int tid = threadIdx.x;
  const int gx = gridDim.x;
  int flat = blockIdx.y * gx + blockIdx.x;
  int nwg = gx * gridDim.y;
  int nb = (nwg & 7) ? flat : ((flat & 7) * (nwg >> 3) + (flat >> 3));
  const int m0 = (nb / gx) << 7;
  const int n0 = (nb % gx) << 7;
  const int w = tid >> 6, lane = tid & 63;
  const int wr = (w >> 1) << 6, wc = (w & 1) << 6;
  const int lr = lane & 15, lg = lane >> 4;
  f32x4 acc[4][4] = {};
  const int sr = tid >> 2, skk = ((tid & 3) << 3) ^ KSWZ(tid >> 2);
  const _Float16* Ag = A + (size_t)(m0 + sr) * K + skk;
  const _Float16* Bg = BT + (size_t)(n0 + sr) * K + skk;
  const size_t halfstep = (size_t)64 * K;
#define GSTAGE(bufi, k0) do { \
    gload_lds16(Ag + (k0),            &As[bufi][(size_t)tid * 8]); \
    gload_lds16(Ag + (k0) + halfstep, &As[bufi][(size_t)(256 + tid) * 8]); \
    gload_lds16(Bg + (k0),            &Bs[bufi][(size_t)tid * 8]); \
    gload_lds16(Bg + (k0) + halfstep, &Bs[bufi][(size_t)(256 + tid) * 8]); \
  } while (0)
  const int nsteps = K >> 5;                 // K/32, >= 8 for all our GEMMs
  GSTAGE(0, 0);
  GSTAGE(1, 32);
  int cur = 0;
  for (int t = 0; t < nsteps; ++t) {
    // wait for buf[cur]'s stage (issued 2 steps back); keep newest stage in flight
    if (t + 1 < nsteps) {
      asm volatile("s_waitcnt vmcnt(4)" ::: "memory");
    } else {
      asm volatile("s_waitcnt vmcnt(0)" ::: "memory");
    }
    __builtin_amdgcn_s_barrier();            // raw barrier: no vmcnt(0) drain
    half8 af[4], bf[4];
#pragma unroll
    for (int tt = 0; tt < 4; ++tt) {
      int rowA = wr + tt * 16 + lr;
      af[tt] = *(const half8*)&As[cur][rowA * 32 + ((lg * 8) ^ KSWZ(rowA))];
    }
#pragma unroll
    for (int tt = 0; tt < 4; ++tt) {
      int rowB = wc + tt * 16 + lr;
      bf[tt] = *(const half8*)&Bs[cur][rowB * 32 + ((lg * 8) ^ KSWZ(rowB))];
    }
#pragma unroll
    for (int i = 0; i < 4; ++i)
#pragma unroll
      for (int j = 0; j < 4; ++j)
        acc[i][j] = __builtin_amdgcn_mfma_f32_16x16x32_f16(af[i], bf[j], acc[i][j], 0, 0, 0);
    if (t + 2 < nsteps) {
      int nxt = cur + 2; if (nxt >= 3) nxt -= 3;
      GSTAGE(nxt, (t + 2) * 32);             // lands after this barrier -> no race
    }
    cur = (cur == 2) ? 0 : cur + 1;
  }
#undef GSTAGE
  float bv[4];
#pragma unroll
  for (int j = 0; j < 4; ++j) bv[j] = bias[n0 + wc + j * 16 + lr];
#pragma unroll
  for (int i = 0; i < 4; ++i) {
#pragma unroll
    for (int j = 0; j < 4; ++j) {
      int row = m0 + wr + i * 16 + lg * 4;
      int col = n0 + wc + j * 16 + lr;
      _Float16* cp = C + (size_t)row * N + col;
#pragma unroll
      for (int rr = 0; rr < 4; ++rr) {
        float v = acc[i][j][rr] + bv[j];
        if (RELU) v = fmaxf(v, 0.0f);
        cp[(size_t)rr * N] = (_Float16)v;
      }
    }
  }
}

// ---------------- MFMA attention: one block per window, 4 waves x 2 heads ---------
// T5: s_setprio(1) around MFMA clusters (independent blocks at different phases).
#define ATT_SWZ(row, col) (((row) << 6) + ((col) ^ (((row) & 7) << 3)))
__global__ __launch_bounds__(256, 3) void attn_mfma(const _Float16* __restrict__ qkv,
    const float* __restrict__ bw, _Float16* __restrict__ o) {
  const int wdw = blockIdx.x;          // window 0..2047
  const int w = threadIdx.x >> 6;      // wave 0..3
  const int lane = threadIdx.x & 63;
  const int lr = lane & 15, lg = lane >> 4;
  __shared__ _Float16 lds_p[4][64 * 64];   // P [64 q][64 k] f16, swizzled
  __shared__ _Float16 lds_v[4][32 * 64];   // V^T [32 d][64 j] f16, swizzled
  _Float16* Pb = lds_p[w];
  _Float16* Vt = lds_v[w];
  const size_t base = (size_t)wdw * 49152;   // 64*768 f16 elems
  f32x4 blv[4];
#pragma unroll
  for (int jt = 0; jt < 4; ++jt) {
    f32x4 bv = *(const f32x4*)&bw[wdw * 64 + jt * 16 + lg * 4];
    blv[jt] = bv * 0.0625f + 0.0625f;
  }
  const f32x4 zero4 = {0.f, 0.f, 0.f, 0.f};
#pragma unroll
  for (int hi = 0; hi < 2; ++hi) {
    const int h = w + hi * 4;
    const size_t qo = base + (size_t)h * 32;
    const _Float16* kp = qkv + qo + 256 + (size_t)lr * 768 + lg * 8;
    const _Float16* qp = qkv + qo +       (size_t)lr * 768 + lg * 8;
    half8 ak[4], bq[4];
#pragma unroll
    for (int t = 0; t < 4; ++t) {
      ak[t] = *(const half8*)(kp + (size_t)t * 16 * 768);
      bq[t] = *(const half8*)(qp + (size_t)t * 16 * 768);
    }
    const _Float16* vp = qkv + qo + 512 + (size_t)lane * 768;
#pragma unroll
    for (int e = 0; e < 4; ++e) {
      half8 vv = *(const half8*)(vp + e * 8);
#pragma unroll
      for (int d = 0; d < 8; ++d) Vt[ATT_SWZ(e * 8 + d, lane)] = vv[d];
    }
    f32x4 cst[4][4];
    __builtin_amdgcn_s_setprio(1);
#pragma unroll
    for (int jt = 0; jt < 4; ++jt)
#pragma unroll
      for (int it = 0; it < 4; ++it)
        cst[jt][it] = __builtin_amdgcn_mfma_f32_16x16x32_f16(ak[jt], bq[it], zero4, 0, 0, 0);
    __builtin_amdgcn_s_setprio(0);
#pragma unroll
    for (int it = 0; it < 4; ++it) {
      float m = -1e30f;
#pragma unroll
      for (int jt = 0; jt < 4; ++jt) {
        cst[jt][it] *= blv[jt];
        m = fmaxf(m, fmaxf(fmaxf(cst[jt][it][0], cst[jt][it][1]),
                           fmaxf(cst[jt][it][2], cst[jt][it][3])));
      }
      m = fmaxf(m, __shfl_xor(m, 16, 64));
      m = fmaxf(m, __shfl_xor(m, 32, 64));
      float s = 0.f;
#pragma unroll
      for (int jt = 0; jt < 4; ++jt)
#pragma unroll
        for (int r = 0; r < 4; ++r) {
          float e = __expf(cst[jt][it][r] - m);
          cst[jt][it][r] = e;
          s += e;
        }
      s += __shfl_xor(s, 16, 64);
      s += __shfl_xor(s, 32, 64);
      float inv = 1.0f / s;
#pragma unroll
      for (int jt = 0; jt < 4; ++jt) {
        half4 pv;
#pragma unroll
        for (int r = 0; r < 4; ++r) pv[r] = (_Float16)(cst[jt][it][r] * inv);
        *(half4*)&Pb[ATT_SWZ(it * 16 + lr, jt * 16 + lg * 4)] = pv;
      }
    }
    f32x4 co[4][2] = {};
#pragma unroll
    for (int ks = 0; ks < 2; ++ks) {
      half8 bv2[2], pa[4];
#pragma unroll
      for (int dt = 0; dt < 2; ++dt)
        bv2[dt] = *(const half8*)&Vt[ATT_SWZ(dt * 16 + lr, ks * 32 + lg * 8)];
#pragma unroll
      for (int it = 0; it < 4; ++it)
        pa[it] = *(const half8*)&Pb[ATT_SWZ(it * 16 + lr, ks * 32 + lg * 8)];
      __builtin_amdgcn_s_setprio(1);
#pragma unroll
      for (int it = 0; it < 4; ++it)
#pragma unroll
        for (int dt = 0; dt < 2; ++dt)
          co[it][dt] = __builtin_amdgcn_mfma_f32_16x16x32_f16(pa[it], bv2[dt], co[it][dt], 0, 0, 0);
      __builtin_amdgcn_s_setprio(0);
    }
#pragma unroll
    for (int it = 0; it < 4; ++it)
#pragma unroll
      for (int dt = 0; dt < 2; ++dt)
#pragma unroll
        for (int r = 0; r < 4; ++r) {
          int row = it * 16 + lg * 4 + r;
          o[((size_t)wdw * 64 + row) * 256 + h * 32 + dt * 16 + lr] =
              (_Float16)co[it][dt][r];
        }
  }
}

// ---------------- out = resid + LayerNorm(inp)*g + b  (wave per row, C=256) -------
__global__ __launch_bounds__(256) void ln_add(const _Float16* __restrict__ inp,
    const _Float16* __restrict__ res, const float* __restrict__ gg,
    const float* __restrict__ bb, _Float16* __restrict__ out) {
  const int w = threadIdx.x >> 6, lane = threadIdx.x & 63;
  const size_t row = (size_t)blockIdx.x * 4 + w;
  half4 v = ((const half4*)(inp + row * 256))[lane];
  float f0 = (float)v[0], f1 = (float)v[1], f2 = (float)v[2], f3 = (float)v[3];
  float s = f0 + f1 + f2 + f3;
  float s2 = f0*f0 + f1*f1 + f2*f2 + f3*f3;
#pragma unroll
  for (int m = 1; m < 64; m <<= 1) {
    s  += __shfl_xor(s, m, 64);
    s2 += __shfl_xor(s2, m, 64);
  }
  float mu = s * 0.00390625f;
  float var = s2 * 0.00390625f - mu * mu;
  float rs = rsqrtf(var + 1e-5f);
  f32x4 gv = *(const f32x4*)(gg + lane * 4);
  f32x4 bv = *(const f32x4*)(bb + lane * 4);
  half4 rv = ((const half4*)(res + row * 256))[lane];
  half4 ov;
  ov[0] = (_Float16)((f0 - mu) * rs * gv[0] + bv[0] + (float)rv[0]);
  ov[1] = (_Float16)((f1 - mu) * rs * gv[1] + bv[1] + (float)rv[1]);
  ov[2] = (_Float16)((f2 - mu) * rs * gv[2] + bv[2] + (float)rv[2]);
  ov[3] = (_Float16)((f3 - mu) * rs * gv[3] + bv[3] + (float)rv[3]);
  ((half4*)(out + row * 256))[lane] = ov;
}

__global__ __launch_bounds__(256) void sentinel(float* out, int n) {
  int i = blockIdx.x * 256 + threadIdx.x;
  if (i < n) out[i] = 12345.0f;
}

extern "C" void kernel_launch(void* const* d_in, const int* in_sizes, int n_in,
                              void* d_out, int out_size, void* d_ws, size_t ws_size,
                              hipStream_t stream) {
  const float* x      = (const float*)d_in[0];
  const float* blurm  = (const float*)d_in[1];
  const float* qkv_w  = (const float*)d_in[2];
  const float* qkv_b  = (const float*)d_in[3];
  const float* proj_w = (const float*)d_in[4];
  const float* proj_b = (const float*)d_in[5];
  const float* ff1_w  = (const float*)d_in[6];
  const float* ff1_b  = (const float*)d_in[7];
  const float* ff2_w  = (const float*)d_in[8];
  const float* ff2_b  = (const float*)d_in[9];
  const float* n1_g   = (const float*)d_in[10];
  const float* n1_b   = (const float*)d_in[11];
  const float* n2_g   = (const float*)d_in[12];
  const float* n2_b   = (const float*)d_in[13];
  float* out = (float*)d_out;

  char* ws = (char*)d_ws;
  constexpr size_t OFF_RA  = 0;                          // qkv f16 / ff1-half f16
  constexpr size_t OFF_XW  = 201326592ull;               // xw f16
  constexpr size_t OFF_AO  = OFF_XW + 67108864ull;       // attn out f16
  constexpr size_t OFF_RC  = OFF_AO + 67108864ull;       // proj out / ff2 out f16
  constexpr size_t OFF_X1  = OFF_RC + 67108864ull;       // x1 f16
  constexpr size_t OFF_QW  = OFF_X1 + 67108864ull;
  constexpr size_t OFF_PW  = OFF_QW + 393216ull;
  constexpr size_t OFF_F1W = OFF_PW + 131072ull;
  constexpr size_t OFF_F2W = OFF_F1W + 524288ull;
  constexpr size_t OFF_BL  = OFF_F2W + 524288ull;
  constexpr size_t NEED    = OFF_BL + 524288ull;
  if (ws_size < NEED) {
    sentinel<<<(out_size + 255) / 256, 256, 0, stream>>>(out, out_size);
    return;
  }
  _Float16* RA   = (_Float16*)(ws + OFF_RA);
  _Float16* xw_h = (_Float16*)(ws + OFF_XW);
  _Float16* ao   = (_Float16*)(ws + OFF_AO);
  _Float16* rc   = (_Float16*)(ws + OFF_RC);
  _Float16* x1h  = (_Float16*)(ws + OFF_X1);
  _Float16* qwT  = (_Float16*)(ws + OFF_QW);
  _Float16* pwT  = (_Float16*)(ws + OFF_PW);
  _Float16* f1wT = (_Float16*)(ws + OFF_F1W);
  _Float16* f2wT = (_Float16*)(ws + OFF_F2W);
  float* blurw   = (float*)(ws + OFF_BL);

  wtrans_all<<<3072, 256, 0, stream>>>(qkv_w, proj_w, ff1_w, ff2_w, qwT, pwT, f1wT, f2wT);
  blur_prep<<<512, 256, 0, stream>>>(blurm, blurw);
  gather_x<<<dim3(4, 128, 8), 256, 0, stream>>>(x, xw_h);

  // qkv = xw @ qkv_w + b          [131072, 768]
  gemm_f16<0><<<dim3(6, 1024), 256, 0, stream>>>(xw_h, qwT, qkv_b, RA, 131072, 768, 256);
  // windowed blur-modulated MFMA attention -> [131072, 256]
  attn_mfma<<<2048, 256, 0, stream>>>(RA, blurw, ao);
  // proj
  gemm_f16<0><<<dim3(2, 1024), 256, 0, stream>>>(ao, pwT, proj_b, rc, 131072, 256, 256);
  // x1 = xw + LN1(proj)
  ln_add<<<32768, 256, 0, stream>>>(rc, xw_h, n1_g, n1_b, x1h);
  // ff in two M-halves (measured best)
  for (int ch = 0; ch < 2; ++ch) {
    const size_t off = (size_t)ch * 65536 * 256;
    gemm_f16<1><<<dim3(8, 512), 256, 0, stream>>>(x1h + off, f1wT, ff1_b,
                                                  RA, 65536, 1024, 256);
    gemm_f16<0><<<dim3(2, 512), 256, 0, stream>>>(RA, f2wT, ff2_b,
                                                  rc + off, 65536, 256, 1024);
  }
  // fused: x2 = x1 + LN2(rc) -> window reverse -> out  (removes xw round-trip)
  ln_scatter<<<dim3(128, 8), 256, 0, stream>>>(rc, x1h, n2_g, n2_b, out);
}

// Round 16
// 585.059 us; speedup vs baseline: 1.3483x; 1.0026x over previous
//
#include <hip/hip_runtime.h>
#include <hip/hip_bf16.h>
#include <cstdint>

typedef _Float16 half8 __attribute__((ext_vector_type(8)));
typedef _Float16 half4 __attribute__((ext_vector_type(4)));
typedef float f32x4 __attribute__((ext_vector_type(4)));

__device__ __forceinline__ void gload_lds16(const _Float16* g, _Float16* l) {
  __builtin_amdgcn_global_load_lds(
      (const __attribute__((address_space(1))) void*)g,
      (__attribute__((address_space(3))) void*)l, 16, 0, 0);
}

// LDS col swizzle for 32-elem (64 B) rows, 16 B granular, involution.
#define KSWZ(r) ((((r) >> 1) & 3) << 3)

// ------- merged weight transposes: WT[n][k] = W[k][n], f32 -> f16 (one launch) ----
__global__ __launch_bounds__(256) void wtrans_all(
    const float* __restrict__ qkv_w, const float* __restrict__ proj_w,
    const float* __restrict__ ff1_w, const float* __restrict__ ff2_w,
    _Float16* __restrict__ qwT, _Float16* __restrict__ pwT,
    _Float16* __restrict__ f1T, _Float16* __restrict__ f2T) {
  const int b = blockIdx.x;
  const float* W; _Float16* WT; int K, N, idx;
  if (b < 768)       { W = qkv_w;  WT = qwT; K = 256;  N = 768;  idx = b * 256 + threadIdx.x; }
  else if (b < 1024) { W = proj_w; WT = pwT; K = 256;  N = 256;  idx = (b - 768) * 256 + threadIdx.x; }
  else if (b < 2048) { W = ff1_w;  WT = f1T; K = 256;  N = 1024; idx = (b - 1024) * 256 + threadIdx.x; }
  else               { W = ff2_w;  WT = f2T; K = 1024; N = 256;  idx = (b - 2048) * 256 + threadIdx.x; }
  int k = idx / N, n = idx - k * N;
  WT[(size_t)n * K + k] = (_Float16)W[idx];
}

// ---------------- blur bilinear upsample 32x32 -> 128x128, windowed [nw][64] ------
__global__ __launch_bounds__(256) void blur_prep(const float* __restrict__ bm,
                                                 float* __restrict__ bw) {
  int idx = blockIdx.x * 256 + threadIdx.x;   // 0..131071
  int wi = idx >> 6, t = idx & 63;
  int b = wi >> 8, wid = wi & 255;
  int hw = wid >> 4, ww = wid & 15;
  int hh = hw * 8 + (t >> 3), www = ww * 8 + (t & 7);
  float yf = (hh + 0.5f) * 0.25f - 0.5f;
  float xf = (www + 0.5f) * 0.25f - 0.5f;
  float yfl = floorf(yf), xfl = floorf(xf);
  float fy = yf - yfl, fx = xf - xfl;
  int y0 = (int)yfl, x0 = (int)xfl;
  int y1 = y0 + 1, x1 = x0 + 1;
  if (y0 < 0) y0 = 0; if (x0 < 0) x0 = 0;
  if (y1 > 31) y1 = 31; if (x1 > 31) x1 = 31;
  const float* p = bm + (size_t)b * 1024;
  float v00 = p[y0 * 32 + x0], v01 = p[y0 * 32 + x1];
  float v10 = p[y1 * 32 + x0], v11 = p[y1 * 32 + x1];
  float v0 = v00 + fx * (v01 - v00);
  float v1 = v10 + fx * (v11 - v10);
  bw[idx] = v0 + fy * (v1 - v0);
}

// ---------------- gather x [B,C,H,W] f32 -> xw [nw*64][256] f16 -------------------
__global__ __launch_bounds__(256) void gather_x(const float* __restrict__ x,
                                                _Float16* __restrict__ xw) {
  const int c0 = blockIdx.x << 6;   // 0,64,128,192
  const int hh = blockIdx.y;        // 0..127
  const int b  = blockIdx.z;        // 0..7
  __shared__ float tile[64][133];
  const int tid = threadIdx.x;
  {
    const int cl = tid >> 7, p = tid & 127;
    const float* xp = x + ((size_t)(b * 256 + c0) * 128 + hh) * 128 + p;
#pragma unroll
    for (int i = 0; i < 32; ++i) {
      int c = i * 2 + cl;
      tile[c][p] = xp[(size_t)c * 16384];
    }
  }
  __syncthreads();
  const int w = tid >> 6, lane = tid & 63;
  const int hw = hh >> 3, ts = hh & 7;
#pragma unroll
  for (int i = 0; i < 32; ++i) {
    int pp = i * 4 + w;
    int row = ((b * 256 + hw * 16 + (pp >> 3)) << 6) + ts * 8 + (pp & 7);
    xw[(size_t)row * 256 + c0 + lane] = (_Float16)tile[lane][pp];
  }
}

// ------- fused: x2 = x1 + LN2(rc)  ->  window-reverse  ->  out [B,C,H,W] f32 ------
__global__ __launch_bounds__(256) void ln_scatter(const _Float16* __restrict__ rc,
    const _Float16* __restrict__ x1, const float* __restrict__ gg,
    const float* __restrict__ bb, float* __restrict__ out) {
  const int hh = blockIdx.x;   // 0..127
  const int b  = blockIdx.y;   // 0..7
  __shared__ _Float16 tile[128][258];
  const int w = threadIdx.x >> 6, lane = threadIdx.x & 63;
  const int hw = hh >> 3, ts = hh & 7;
  f32x4 gv = *(const f32x4*)(gg + lane * 4);
  f32x4 bv = *(const f32x4*)(bb + lane * 4);
#pragma unroll
  for (int i = 0; i < 32; ++i) {
    const int pp = w * 32 + i;   // pixel x 0..127
    const size_t row = ((size_t)(b * 256 + hw * 16 + (pp >> 3)) << 6) + ts * 8 + (pp & 7);
    half4 v  = ((const half4*)(rc + row * 256))[lane];
    half4 rv = ((const half4*)(x1 + row * 256))[lane];
    float f0 = (float)v[0], f1 = (float)v[1], f2 = (float)v[2], f3 = (float)v[3];
    float s = f0 + f1 + f2 + f3;
    float s2 = f0*f0 + f1*f1 + f2*f2 + f3*f3;
#pragma unroll
    for (int m = 1; m < 64; m <<= 1) {
      s  += __shfl_xor(s, m, 64);
      s2 += __shfl_xor(s2, m, 64);
    }
    float mu = s * 0.00390625f;
    float var = s2 * 0.00390625f - mu * mu;
    float rs = rsqrtf(var + 1e-5f);
    half4 ov;
    ov[0] = (_Float16)((f0 - mu) * rs * gv[0] + bv[0] + (float)rv[0]);
    ov[1] = (_Float16)((f1 - mu) * rs * gv[1] + bv[1] + (float)rv[1]);
    ov[2] = (_Float16)((f2 - mu) * rs * gv[2] + bv[2] + (float)rv[2]);
    ov[3] = (_Float16)((f3 - mu) * rs * gv[3] + bv[3] + (float)rv[3]);
    *(half4*)&tile[pp][lane * 4] = ov;
  }
  __syncthreads();
  const int cl = threadIdx.x >> 7, p = threadIdx.x & 127;
  float* op = out + ((size_t)(b * 256) * 128 + hh) * 128 + p;
#pragma unroll
  for (int i = 0; i < 128; ++i) {
    int c = i * 2 + cl;
    op[(size_t)c * 16384] = (float)tile[p][c];
  }
}

// ---------------- f16 MFMA GEMM: C[M][N] = A[M][K] * BT[N][K]^T + bias ------------
// 128x128 tile, BK=32, 512 threads (8 waves, 2Mx4N, 64x32 per wave).
// T1 XCD-swizzle + KSWZ LDS; 3-buffer, 2-deep prefetch, raw s_barrier +
// counted vmcnt(2) (1 gload/thread/operand per stage). 24 waves/CU resident.
template<int RELU>
__global__ __launch_bounds__(512) void gemm_f16(const _Float16* __restrict__ A,
    const _Float16* __restrict__ BT, const float* __restrict__ bias,
    _Float16* __restrict__ C, int M, int N, int K) {
  __shared__ _Float16 As[3][128 * 32];
  __shared__ _Float16 Bs[3][128 * 32];
  const int tid = threadIdx.x;
  const int gx = gridDim.x;
  int flat = blockIdx.y * gx + blockIdx.x;
  int nwg = gx * gridDim.y;
  int nb = (nwg & 7) ? flat : ((flat & 7) * (nwg >> 3) + (flat >> 3));
  const int m0 = (nb / gx) << 7;
  const int n0 = (nb % gx) << 7;
  const int w = tid >> 6, lane = tid & 63;
  const int wr = (w >> 2) << 6;        // 0 / 64
  const int wc = (w & 3) << 5;         // 0 / 32 / 64 / 96
  const int lr = lane & 15, lg = lane >> 4;
  f32x4 acc[4][2] = {};
  const int sr = tid >> 2;                              // 0..127: tile row
  const int skk = ((tid & 3) << 3) ^ KSWZ(tid >> 2);    // pre-swizzled col
  const _Float16* Ag = A + (size_t)(m0 + sr) * K + skk;
  const _Float16* Bg = BT + (size_t)(n0 + sr) * K + skk;
#define GSTAGE(bufi, k0) do { \
    gload_lds16(Ag + (k0), &As[bufi][(size_t)tid * 8]); \
    gload_lds16(Bg + (k0), &Bs[bufi][(size_t)tid * 8]); \
  } while (0)
  const int nsteps = K >> 5;                 // K/32, >= 8 for all our GEMMs
  GSTAGE(0, 0);
  GSTAGE(1, 32);
  int cur = 0;
  for (int t = 0; t < nsteps; ++t) {
    // wait for buf[cur]'s stage (issued 2 steps back); keep newest stage in flight
    if (t + 1 < nsteps) {
      asm volatile("s_waitcnt vmcnt(2)" ::: "memory");
    } else {
      asm volatile("s_waitcnt vmcnt(0)" ::: "memory");
    }
    __builtin_amdgcn_s_barrier();            // raw barrier: no vmcnt(0) drain
    half8 af[4], bf[2];
#pragma unroll
    for (int tt = 0; tt < 4; ++tt) {
      int rowA = wr + tt * 16 + lr;
      af[tt] = *(const half8*)&As[cur][rowA * 32 + ((lg * 8) ^ KSWZ(rowA))];
    }
#pragma unroll
    for (int tt = 0; tt < 2; ++tt) {
      int rowB = wc + tt * 16 + lr;
      bf[tt] = *(const half8*)&Bs[cur][rowB * 32 + ((lg * 8) ^ KSWZ(rowB))];
    }
#pragma unroll
    for (int i = 0; i < 4; ++i)
#pragma unroll
      for (int j = 0; j < 2; ++j)
        acc[i][j] = __builtin_amdgcn_mfma_f32_16x16x32_f16(af[i], bf[j], acc[i][j], 0, 0, 0);
    if (t + 2 < nsteps) {
      int nxt = cur + 2; if (nxt >= 3) nxt -= 3;
      GSTAGE(nxt, (t + 2) * 32);             // lands after this barrier -> no race
    }
    cur = (cur == 2) ? 0 : cur + 1;
  }
#undef GSTAGE
  float bv[2];
#pragma unroll
  for (int j = 0; j < 2; ++j) bv[j] = bias[n0 + wc + j * 16 + lr];
#pragma unroll
  for (int i = 0; i < 4; ++i) {
#pragma unroll
    for (int j = 0; j < 2; ++j) {
      int row = m0 + wr + i * 16 + lg * 4;
      int col = n0 + wc + j * 16 + lr;
      _Float16* cp = C + (size_t)row * N + col;
#pragma unroll
      for (int rr = 0; rr < 4; ++rr) {
        float v = acc[i][j][rr] + bv[j];
        if (RELU) v = fmaxf(v, 0.0f);
        cp[(size_t)rr * N] = (_Float16)v;
      }
    }
  }
}

// ---------------- MFMA attention: one block per window, 4 waves x 2 heads ---------
// T5: s_setprio(1) around MFMA clusters (independent blocks at different phases).
#define ATT_SWZ(row, col) (((row) << 6) + ((col) ^ (((row) & 7) << 3)))
__global__ __launch_bounds__(256, 3) void attn_mfma(const _Float16* __restrict__ qkv,
    const float* __restrict__ bw, _Float16* __restrict__ o) {
  const int wdw = blockIdx.x;          // window 0..2047
  const int w = threadIdx.x >> 6;      // wave 0..3
  const int lane = threadIdx.x & 63;
  const int lr = lane & 15, lg = lane >> 4;
  __shared__ _Float16 lds_p[4][64 * 64];   // P [64 q][64 k] f16, swizzled
  __shared__ _Float16 lds_v[4][32 * 64];   // V^T [32 d][64 j] f16, swizzled
  _Float16* Pb = lds_p[w];
  _Float16* Vt = lds_v[w];
  const size_t base = (size_t)wdw * 49152;   // 64*768 f16 elems
  f32x4 blv[4];
#pragma unroll
  for (int jt = 0; jt < 4; ++jt) {
    f32x4 bv = *(const f32x4*)&bw[wdw * 64 + jt * 16 + lg * 4];
    blv[jt] = bv * 0.0625f + 0.0625f;
  }
  const f32x4 zero4 = {0.f, 0.f, 0.f, 0.f};
#pragma unroll
  for (int hi = 0; hi < 2; ++hi) {
    const int h = w + hi * 4;
    const size_t qo = base + (size_t)h * 32;
    const _Float16* kp = qkv + qo + 256 + (size_t)lr * 768 + lg * 8;
    const _Float16* qp = qkv + qo +       (size_t)lr * 768 + lg * 8;
    half8 ak[4], bq[4];
#pragma unroll
    for (int t = 0; t < 4; ++t) {
      ak[t] = *(const half8*)(kp + (size_t)t * 16 * 768);
      bq[t] = *(const half8*)(qp + (size_t)t * 16 * 768);
    }
    const _Float16* vp = qkv + qo + 512 + (size_t)lane * 768;
#pragma unroll
    for (int e = 0; e < 4; ++e) {
      half8 vv = *(const half8*)(vp + e * 8);
#pragma unroll
      for (int d = 0; d < 8; ++d) Vt[ATT_SWZ(e * 8 + d, lane)] = vv[d];
    }
    f32x4 cst[4][4];
    __builtin_amdgcn_s_setprio(1);
#pragma unroll
    for (int jt = 0; jt < 4; ++jt)
#pragma unroll
      for (int it = 0; it < 4; ++it)
        cst[jt][it] = __builtin_amdgcn_mfma_f32_16x16x32_f16(ak[jt], bq[it], zero4, 0, 0, 0);
    __builtin_amdgcn_s_setprio(0);
#pragma unroll
    for (int it = 0; it < 4; ++it) {
      float m = -1e30f;
#pragma unroll
      for (int jt = 0; jt < 4; ++jt) {
        cst[jt][it] *= blv[jt];
        m = fmaxf(m, fmaxf(fmaxf(cst[jt][it][0], cst[jt][it][1]),
                           fmaxf(cst[jt][it][2], cst[jt][it][3])));
      }
      m = fmaxf(m, __shfl_xor(m, 16, 64));
      m = fmaxf(m, __shfl_xor(m, 32, 64));
      float s = 0.f;
#pragma unroll
      for (int jt = 0; jt < 4; ++jt)
#pragma unroll
        for (int r = 0; r < 4; ++r) {
          float e = __expf(cst[jt][it][r] - m);
          cst[jt][it][r] = e;
          s += e;
        }
      s += __shfl_xor(s, 16, 64);
      s += __shfl_xor(s, 32, 64);
      float inv = 1.0f / s;
#pragma unroll
      for (int jt = 0; jt < 4; ++jt) {
        half4 pv;
#pragma unroll
        for (int r = 0; r < 4; ++r) pv[r] = (_Float16)(cst[jt][it][r] * inv);
        *(half4*)&Pb[ATT_SWZ(it * 16 + lr, jt * 16 + lg * 4)] = pv;
      }
    }
    f32x4 co[4][2] = {};
#pragma unroll
    for (int ks = 0; ks < 2; ++ks) {
      half8 bv2[2], pa[4];
#pragma unroll
      for (int dt = 0; dt < 2; ++dt)
        bv2[dt] = *(const half8*)&Vt[ATT_SWZ(dt * 16 + lr, ks * 32 + lg * 8)];
#pragma unroll
      for (int it = 0; it < 4; ++it)
        pa[it] = *(const half8*)&Pb[ATT_SWZ(it * 16 + lr, ks * 32 + lg * 8)];
      __builtin_amdgcn_s_setprio(1);
#pragma unroll
      for (int it = 0; it < 4; ++it)
#pragma unroll
        for (int dt = 0; dt < 2; ++dt)
          co[it][dt] = __builtin_amdgcn_mfma_f32_16x16x32_f16(pa[it], bv2[dt], co[it][dt], 0, 0, 0);
      __builtin_amdgcn_s_setprio(0);
    }
#pragma unroll
    for (int it = 0; it < 4; ++it)
#pragma unroll
      for (int dt = 0; dt < 2; ++dt)
#pragma unroll
        for (int r = 0; r < 4; ++r) {
          int row = it * 16 + lg * 4 + r;
          o[((size_t)wdw * 64 + row) * 256 + h * 32 + dt * 16 + lr] =
              (_Float16)co[it][dt][r];
        }
  }
}

// ---------------- out = resid + LayerNorm(inp)*g + b  (wave per row, C=256) -------
__global__ __launch_bounds__(256) void ln_add(const _Float16* __restrict__ inp,
    const _Float16* __restrict__ res, const float* __restrict__ gg,
    const float* __restrict__ bb, _Float16* __restrict__ out) {
  const int w = threadIdx.x >> 6, lane = threadIdx.x & 63;
  const size_t row = (size_t)blockIdx.x * 4 + w;
  half4 v = ((const half4*)(inp + row * 256))[lane];
  float f0 = (float)v[0], f1 = (float)v[1], f2 = (float)v[2], f3 = (float)v[3];
  float s = f0 + f1 + f2 + f3;
  float s2 = f0*f0 + f1*f1 + f2*f2 + f3*f3;
#pragma unroll
  for (int m = 1; m < 64; m <<= 1) {
    s  += __shfl_xor(s, m, 64);
    s2 += __shfl_xor(s2, m, 64);
  }
  float mu = s * 0.00390625f;
  float var = s2 * 0.00390625f - mu * mu;
  float rs = rsqrtf(var + 1e-5f);
  f32x4 gv = *(const f32x4*)(gg + lane * 4);
  f32x4 bv = *(const f32x4*)(bb + lane * 4);
  half4 rv = ((const half4*)(res + row * 256))[lane];
  half4 ov;
  ov[0] = (_Float16)((f0 - mu) * rs * gv[0] + bv[0] + (float)rv[0]);
  ov[1] = (_Float16)((f1 - mu) * rs * gv[1] + bv[1] + (float)rv[1]);
  ov[2] = (_Float16)((f2 - mu) * rs * gv[2] + bv[2] + (float)rv[2]);
  ov[3] = (_Float16)((f3 - mu) * rs * gv[3] + bv[3] + (float)rv[3]);
  ((half4*)(out + row * 256))[lane] = ov;
}

__global__ __launch_bounds__(256) void sentinel(float* out, int n) {
  int i = blockIdx.x * 256 + threadIdx.x;
  if (i < n) out[i] = 12345.0f;
}

extern "C" void kernel_launch(void* const* d_in, const int* in_sizes, int n_in,
                              void* d_out, int out_size, void* d_ws, size_t ws_size,
                              hipStream_t stream) {
  const float* x      = (const float*)d_in[0];
  const float* blurm  = (const float*)d_in[1];
  const float* qkv_w  = (const float*)d_in[2];
  const float* qkv_b  = (const float*)d_in[3];
  const float* proj_w = (const float*)d_in[4];
  const float* proj_b = (const float*)d_in[5];
  const float* ff1_w  = (const float*)d_in[6];
  const float* ff1_b  = (const float*)d_in[7];
  const float* ff2_w  = (const float*)d_in[8];
  const float* ff2_b  = (const float*)d_in[9];
  const float* n1_g   = (const float*)d_in[10];
  const float* n1_b   = (const float*)d_in[11];
  const float* n2_g   = (const float*)d_in[12];
  const float* n2_b   = (const float*)d_in[13];
  float* out = (float*)d_out;

  char* ws = (char*)d_ws;
  constexpr size_t OFF_RA  = 0;                          // qkv f16 / ff1-half f16
  constexpr size_t OFF_XW  = 201326592ull;               // xw f16
  constexpr size_t OFF_AO  = OFF_XW + 67108864ull;       // attn out f16
  constexpr size_t OFF_RC  = OFF_AO + 67108864ull;       // proj out / ff2 out f16
  constexpr size_t OFF_X1  = OFF_RC + 67108864ull;       // x1 f16
  constexpr size_t OFF_QW  = OFF_X1 + 67108864ull;
  constexpr size_t OFF_PW  = OFF_QW + 393216ull;
  constexpr size_t OFF_F1W = OFF_PW + 131072ull;
  constexpr size_t OFF_F2W = OFF_F1W + 524288ull;
  constexpr size_t OFF_BL  = OFF_F2W + 524288ull;
  constexpr size_t NEED    = OFF_BL + 524288ull;
  if (ws_size < NEED) {
    sentinel<<<(out_size + 255) / 256, 256, 0, stream>>>(out, out_size);
    return;
  }
  _Float16* RA   = (_Float16*)(ws + OFF_RA);
  _Float16* xw_h = (_Float16*)(ws + OFF_XW);
  _Float16* ao   = (_Float16*)(ws + OFF_AO);
  _Float16* rc   = (_Float16*)(ws + OFF_RC);
  _Float16* x1h  = (_Float16*)(ws + OFF_X1);
  _Float16* qwT  = (_Float16*)(ws + OFF_QW);
  _Float16* pwT  = (_Float16*)(ws + OFF_PW);
  _Float16* f1wT = (_Float16*)(ws + OFF_F1W);
  _Float16* f2wT = (_Float16*)(ws + OFF_F2W);
  float* blurw   = (float*)(ws + OFF_BL);

  wtrans_all<<<3072, 256, 0, stream>>>(qkv_w, proj_w, ff1_w, ff2_w, qwT, pwT, f1wT, f2wT);
  blur_prep<<<512, 256, 0, stream>>>(blurm, blurw);
  gather_x<<<dim3(4, 128, 8), 256, 0, stream>>>(x, xw_h);

  // qkv = xw @ qkv_w + b          [131072, 768]
  gemm_f16<0><<<dim3(6, 1024), 512, 0, stream>>>(xw_h, qwT, qkv_b, RA, 131072, 768, 256);
  // windowed blur-modulated MFMA attention -> [131072, 256]
  attn_mfma<<<2048, 256, 0, stream>>>(RA, blurw, ao);
  // proj
  gemm_f16<0><<<dim3(2, 1024), 512, 0, stream>>>(ao, pwT, proj_b, rc, 131072, 256, 256);
  // x1 = xw + LN1(proj)
  ln_add<<<32768, 256, 0, stream>>>(rc, xw_h, n1_g, n1_b, x1h);
  // ff in two M-halves (measured best)
  for (int ch = 0; ch < 2; ++ch) {
    const size_t off = (size_t)ch * 65536 * 256;
    gemm_f16<1><<<dim3(8, 512), 512, 0, stream>>>(x1h + off, f1wT, ff1_b,
                                                  RA, 65536, 1024, 256);
    gemm_f16<0><<<dim3(2, 512), 512, 0, stream>>>(RA, f2wT, ff2_b,
                                                  rc + off, 65536, 256, 1024);
  }
  // fused: x2 = x1 + LN2(rc) -> window reverse -> out  (removes xw round-trip)
  ln_scatter<<<dim3(128, 8), 256, 0, stream>>>(rc, x1h, n2_g, n2_b, out);
}